// Round 1
// baseline (371.155 us; speedup 1.0000x reference)
//
#include <hip/hip_runtime.h>
#include <cstddef>

// Problem constants (fixed by setup_inputs).
#define E_ 1024
#define H_ 16
#define HD_ 64
#define B_ 2
#define S_ 1024
#define NSEG 16
#define SEGLEN (S_/NSEG)
#define CHUNKS 8
#define CHLEN (S_/CHUNKS)
#define SCALE 0.03125f   // 1/sqrt(E)

// ---- workspace layout (float offsets) ----
#define Q_OFF   0
#define R_OFF   (B_*S_*E_)
#define PK_OFF  (2*B_*S_*E_)
#define PV_OFF  (PK_OFF + B_*CHUNKS*E_)
#define KS_OFF  (PV_OFF + B_*CHUNKS*E_)
#define VS_OFF  (KS_OFF + B_*E_)
#define WVB_OFF (VS_OFF + B_*E_)
#define RS_OFF  (WVB_OFF + B_*H_*E_)
#define SEG_OFF (RS_OFF + B_*H_*S_)
// total = 2*2M + 2*16K + 2*2K + 32K + 32K + 32K floats ~= 17.3 MB

// K1: partial column sums of key and value over s-chunks.
__global__ __launch_bounds__(256) void k1_colsum_partial(
    const float* __restrict__ key, const float* __restrict__ value,
    float* __restrict__ pk, float* __restrict__ pv) {
  int idx = blockIdx.x*256 + threadIdx.x;
  int e = idx % E_;
  int c = (idx / E_) % CHUNKS;
  int b = idx / (E_*CHUNKS);
  const float* kp = key   + ((size_t)(b*S_ + c*CHLEN))*E_ + e;
  const float* vp = value + ((size_t)(b*S_ + c*CHLEN))*E_ + e;
  float sk = 0.f, sv = 0.f;
  #pragma unroll 4
  for (int s = 0; s < CHLEN; ++s) {
    sk += kp[(size_t)s*E_];
    sv += vp[(size_t)s*E_];
  }
  pk[(b*CHUNKS + c)*E_ + e] = sk;
  pv[(b*CHUNKS + c)*E_ + e] = sv;
}

// K2: ksum[b,:] = colsum(key) @ Wk + S*bk ; vsum likewise.
// 64 blocks: (job 2) x (b 2) x (n-tile 16). Block reduces full colsum into LDS.
__global__ __launch_bounds__(256) void k2_small_gemm(
    const float* __restrict__ pk, const float* __restrict__ pv,
    const float* __restrict__ Wk, const float* __restrict__ bk,
    const float* __restrict__ Wv, const float* __restrict__ bv,
    float* __restrict__ ksum, float* __restrict__ vsum) {
  __shared__ float colsum[E_];
  __shared__ float red[4][64];
  int bi = blockIdx.x;
  int j  = bi >> 5;          // 0: key, 1: value
  int b  = (bi >> 4) & 1;
  int nt = bi & 15;
  int t = threadIdx.x;
  const float* p    = j ? pv : pk;
  const float* W    = j ? Wv : Wk;
  const float* bias = j ? bv : bk;
  float* out        = j ? vsum : ksum;
  for (int i = t; i < E_; i += 256) {
    float s = 0.f;
    #pragma unroll
    for (int c = 0; c < CHUNKS; ++c) s += p[(b*CHUNKS + c)*E_ + i];
    colsum[i] = s;
  }
  __syncthreads();
  int tx = t & 63, ty = t >> 6;
  int n = nt*64 + tx;
  float partial = 0.f;
  #pragma unroll 4
  for (int e = ty*256; e < ty*256 + 256; ++e)
    partial += colsum[e] * W[(size_t)e*E_ + n];
  red[ty][tx] = partial;
  __syncthreads();
  if (ty == 0) {
    float v = red[0][tx] + red[1][tx] + red[2][tx] + red[3][tx]
            + (float)S_ * bias[n];
    out[b*E_ + n] = v;
  }
}

// K3: WV[b,h,n] = sum_d vsum[b,h*64+d] * Wo[h*64+d, n]
__global__ __launch_bounds__(256) void k3_wv(
    const float* __restrict__ vsum, const float* __restrict__ Wo,
    float* __restrict__ WV) {
  int idx = blockIdx.x*256 + threadIdx.x;
  int n = idx % E_;
  int h = (idx / E_) % H_;
  int b = idx / (E_*H_);
  float acc = 0.f;
  #pragma unroll 8
  for (int d = 0; d < HD_; ++d)
    acc += vsum[b*E_ + h*HD_ + d] * Wo[(size_t)(h*HD_ + d)*E_ + n];
  WV[idx] = acc;
}

// K4: the two big fp32 GEMMs. z=0: Cq = query@Wq + bq ; z=1: Cp = pos@Wp
#define BM 128
#define BN 128
#define BK 8
__global__ __launch_bounds__(256) void k4_sgemm(
    const float* __restrict__ Aq, const float* __restrict__ Wq, const float* __restrict__ bq,
    const float* __restrict__ Ap, const float* __restrict__ Wp,
    float* __restrict__ Cq, float* __restrict__ Cp) {
  const float* A; const float* W; const float* bias; float* C;
  if (blockIdx.z == 0) { A = Aq; W = Wq; bias = bq;      C = Cq; }
  else                 { A = Ap; W = Wp; bias = nullptr; C = Cp; }
  const int K = E_, N = E_;
  __shared__ float As[BK][BM];
  __shared__ float Bs[BK][BN];
  int t = threadIdx.x;
  int bm = blockIdx.y, bn = blockIdx.x;
  int arow = t >> 1,  acol = (t & 1) * 4;
  int brow = t >> 5,  bcol = (t & 31) * 4;
  const float* Aptr = A + ((size_t)(bm*BM + arow))*K + acol;
  const float* Wptr = W + (size_t)brow*N + bn*BN + bcol;
  int ry = (t >> 4) * 8, cx = (t & 15) * 8;
  float acc[8][8] = {};
  for (int kt = 0; kt < K/BK; ++kt) {
    float4 av = *(const float4*)Aptr;
    float4 bv = *(const float4*)Wptr;
    __syncthreads();
    As[acol+0][arow] = av.x;
    As[acol+1][arow] = av.y;
    As[acol+2][arow] = av.z;
    As[acol+3][arow] = av.w;
    *(float4*)&Bs[brow][bcol] = bv;
    __syncthreads();
    Aptr += BK;
    Wptr += (size_t)BK * N;
    #pragma unroll
    for (int k = 0; k < BK; ++k) {
      float a[8], bb[8];
      *(float4*)&a[0]  = *(const float4*)&As[k][ry];
      *(float4*)&a[4]  = *(const float4*)&As[k][ry+4];
      *(float4*)&bb[0] = *(const float4*)&Bs[k][cx];
      *(float4*)&bb[4] = *(const float4*)&Bs[k][cx+4];
      #pragma unroll
      for (int i = 0; i < 8; ++i)
        #pragma unroll
        for (int jj = 0; jj < 8; ++jj)
          acc[i][jj] += a[i] * bb[jj];
    }
  }
  #pragma unroll
  for (int i = 0; i < 8; ++i) {
    int row = bm*BM + ry + i;
    float* crow = C + (size_t)row*N + bn*BN + cx;
    float vals[8];
    #pragma unroll
    for (int jj = 0; jj < 8; ++jj) {
      vals[jj] = acc[i][jj];
      if (bias) vals[jj] += bias[bn*BN + cx + jj];
    }
    float4 v0, v1;
    v0.x = vals[0]; v0.y = vals[1]; v0.z = vals[2]; v0.w = vals[3];
    v1.x = vals[4]; v1.y = vals[5]; v1.z = vals[6]; v1.w = vals[7];
    *(float4*)(crow)     = v0;
    *(float4*)(crow + 4) = v1;
  }
}

// K5a: per-segment sums of R (for two-level prefix scan).
__global__ __launch_bounds__(256) void k5a_segsum(
    const float* __restrict__ R, float* __restrict__ seg) {
  int idx = blockIdx.x*256 + threadIdx.x;
  int e = idx % E_;
  int g = (idx / E_) % NSEG;
  int b = idx / (E_*NSEG);
  const float* p = R + ((size_t)(b*S_ + g*SEGLEN))*E_ + e;
  float s = 0.f;
  #pragma unroll 4
  for (int i = 0; i < SEGLEN; ++i) s += p[(size_t)i*E_];
  seg[(b*NSEG + g)*E_ + e] = s;
}

// K5b: in-place inclusive prefix scan of R along s (per b,e column).
__global__ __launch_bounds__(256) void k5b_scan(
    float* __restrict__ R, const float* __restrict__ seg) {
  int idx = blockIdx.x*256 + threadIdx.x;
  int e = idx % E_;
  int g = (idx / E_) % NSEG;
  int b = idx / (E_*NSEG);
  float run = 0.f;
  for (int gp = 0; gp < g; ++gp) run += seg[(b*NSEG + gp)*E_ + e];
  float* p = R + ((size_t)(b*S_ + g*SEGLEN))*E_ + e;
  for (int i = 0; i < SEGLEN; ++i) {
    run += p[(size_t)i*E_];
    p[(size_t)i*E_] = run;
  }
}

// K6: score row-sums. One wave per (b,h,q); lane = d within head.
// rs[b,h,q] = ( (qp+U)·ksum + (qp+V)·(Rtot - Rpre[S-2-q]) + (qp1+V)·Rpre[S-q-3] ) / sqrt(E)
__global__ __launch_bounds__(256) void k6_rs(
    const float* __restrict__ qp, const float* __restrict__ Rpre,
    const float* __restrict__ ksum, const float* __restrict__ U,
    const float* __restrict__ V, float* __restrict__ rs) {
  int w    = blockIdx.x*4 + (threadIdx.x >> 6);
  int lane = threadIdx.x & 63;
  int q = w % S_;
  int h = (w / S_) % H_;
  int b = w / (S_*H_);
  int he = h*HD_ + lane;
  float qv0  = qp[((size_t)(b*S_ + q))*E_ + he];
  float u    = U[he], vv = V[he];
  float ks   = ksum[b*E_ + he];
  float rtot = Rpre[((size_t)(b*S_ + (S_-1)))*E_ + he];
  float tail = rtot;
  if (q <= S_-2) tail -= Rpre[((size_t)(b*S_ + (S_-2-q)))*E_ + he];
  float p = (qv0 + u)*ks + (qv0 + vv)*tail;
  if (q <= S_-3) {
    float qv1 = qp[((size_t)(b*S_ + q + 1))*E_ + he];
    float hd  = Rpre[((size_t)(b*S_ + (S_-3-q)))*E_ + he];
    p += (qv1 + vv)*hd;
  }
  #pragma unroll
  for (int off = 32; off >= 1; off >>= 1)
    p += __shfl_xor(p, off);
  if (lane == 0) rs[(b*H_ + h)*S_ + q] = p * SCALE;
}

// K7: out[b,q,n] = sum_h rs[b,h,q]*WV[b,h,n] + bo[n]
__global__ __launch_bounds__(256) void k7_out(
    const float* __restrict__ rs, const float* __restrict__ WV,
    const float* __restrict__ bo, float* __restrict__ out) {
  int idx = blockIdx.x*256 + threadIdx.x;
  int n = idx % E_;
  int q = (idx / E_) % S_;
  int b = idx / (E_*S_);
  float acc = bo[n];
  #pragma unroll
  for (int h = 0; h < H_; ++h)
    acc += rs[(b*H_ + h)*S_ + q] * WV[((size_t)(b*H_ + h))*E_ + n];
  out[idx] = acc;
}

extern "C" void kernel_launch(void* const* d_in, const int* in_sizes, int n_in,
                              void* d_out, int out_size, void* d_ws, size_t ws_size,
                              hipStream_t stream) {
  const float* query = (const float*)d_in[0];
  const float* key   = (const float*)d_in[1];
  const float* value = (const float*)d_in[2];
  const float* pos   = (const float*)d_in[3];
  const float* Wq = (const float*)d_in[4];
  const float* bq = (const float*)d_in[5];
  const float* Wk = (const float*)d_in[6];
  const float* bk = (const float*)d_in[7];
  const float* Wv = (const float*)d_in[8];
  const float* bv = (const float*)d_in[9];
  const float* Wp = (const float*)d_in[10];
  const float* U  = (const float*)d_in[11];
  const float* V  = (const float*)d_in[12];
  const float* Wo = (const float*)d_in[13];
  const float* bo = (const float*)d_in[14];
  float* out = (float*)d_out;
  float* ws  = (float*)d_ws;

  float* q_proj = ws + Q_OFF;
  float* Rbuf   = ws + R_OFF;   // R, then prefix-scanned in place
  float* pk     = ws + PK_OFF;
  float* pv     = ws + PV_OFF;
  float* ksum   = ws + KS_OFF;
  float* vsum   = ws + VS_OFF;
  float* WVb    = ws + WVB_OFF;
  float* rs     = ws + RS_OFF;
  float* seg    = ws + SEG_OFF;

  hipLaunchKernelGGL(k1_colsum_partial, dim3(B_*CHUNKS*E_/256), dim3(256), 0, stream,
                     key, value, pk, pv);
  hipLaunchKernelGGL(k2_small_gemm, dim3(64), dim3(256), 0, stream,
                     pk, pv, Wk, bk, Wv, bv, ksum, vsum);
  hipLaunchKernelGGL(k3_wv, dim3(B_*H_*E_/256), dim3(256), 0, stream,
                     vsum, Wo, WVb);
  hipLaunchKernelGGL(k4_sgemm, dim3(E_/BN, B_*S_/BM, 2), dim3(256), 0, stream,
                     query, Wq, bq, pos, Wp, q_proj, Rbuf);
  hipLaunchKernelGGL(k5a_segsum, dim3(B_*NSEG*E_/256), dim3(256), 0, stream,
                     Rbuf, seg);
  hipLaunchKernelGGL(k5b_scan, dim3(B_*NSEG*E_/256), dim3(256), 0, stream,
                     Rbuf, seg);
  hipLaunchKernelGGL(k6_rs, dim3(B_*H_*S_/4), dim3(256), 0, stream,
                     q_proj, Rbuf, ksum, U, V, rs);
  hipLaunchKernelGGL(k7_out, dim3(B_*S_*E_/256), dim3(256), 0, stream,
                     rs, WVb, bo, out);
}

// Round 6
// 243.660 us; speedup vs baseline: 1.5232x; 1.5232x over previous
//
#include <hip/hip_runtime.h>
#include <cstddef>
#include <cstdint>

// Problem constants (fixed by setup_inputs).
#define E_ 1024
#define H_ 16
#define HD_ 64
#define B_ 2
#define S_ 1024
#define NSEG 64
#define SEGLEN (S_/NSEG)          // 16
#define CHUNKS 64
#define CHLEN (S_/CHUNKS)         // 16
#define SCALE 0.03125f            // 1/sqrt(E)

typedef __attribute__((ext_vector_type(8))) short bf16x8;
typedef __attribute__((ext_vector_type(4))) float f32x4;

__device__ __forceinline__ unsigned short f2bf_rne(float x) {
  uint32_t u = __float_as_uint(x);
  uint32_t r = u + 0x7FFFu + ((u >> 16) & 1u);
  return (unsigned short)(r >> 16);
}
__device__ __forceinline__ float bf2f(unsigned short h) {
  return __uint_as_float(((uint32_t)h) << 16);
}
__device__ __forceinline__ void gload_lds16(const void* g, void* l) {
  __builtin_amdgcn_global_load_lds(
      (const __attribute__((address_space(1))) void*)g,
      (__attribute__((address_space(3))) void*)l, 16, 0, 0);
}

// ---------------- kA: per-segment sums of pos (for scan) ----------------
__global__ __launch_bounds__(256) void kA_segsum(
    const float* __restrict__ pos, float* __restrict__ seg) {
  int idx = blockIdx.x*256 + threadIdx.x;
  int e = idx % E_;
  int g = (idx / E_) % NSEG;
  int b = idx / (E_*NSEG);
  const float* p = pos + ((size_t)(b*S_ + g*SEGLEN))*E_ + e;
  float s = 0.f;
  #pragma unroll
  for (int i = 0; i < SEGLEN; ++i) s += p[(size_t)i*E_];
  seg[(b*NSEG + g)*E_ + e] = s;
}

// ---- kB: inclusive prefix-scan of pos along s, fused split-bf16 write ----
// A'p layout: [2048 rows][2048]: cols [0,1024)=hi, [1024,2048)=lo
__global__ __launch_bounds__(256) void kB_scan_split(
    const float* __restrict__ pos, const float* __restrict__ seg,
    unsigned short* __restrict__ Ap) {
  int idx = blockIdx.x*256 + threadIdx.x;
  int e = idx % E_;
  int g = (idx / E_) % NSEG;
  int b = idx / (E_*NSEG);
  float run = 0.f;
  for (int gp = 0; gp < g; ++gp) run += seg[(b*NSEG + gp)*E_ + e];
  const float* p = pos + ((size_t)(b*S_ + g*SEGLEN))*E_ + e;
  #pragma unroll
  for (int i = 0; i < SEGLEN; ++i) {
    run += p[(size_t)i*E_];
    size_t row = (size_t)(b*S_ + g*SEGLEN + i);
    unsigned short hb = f2bf_rne(run);
    float lf = run - bf2f(hb);
    Ap[row*2048 + e]        = hb;
    Ap[row*2048 + 1024 + e] = f2bf_rne(lf);
  }
}

// ---------------- kC: split query into A'q (hi|lo) ----------------
__global__ __launch_bounds__(256) void kC_split_q(
    const float* __restrict__ q, unsigned short* __restrict__ Aq) {
  int idx = blockIdx.x*256 + threadIdx.x;   // 512K threads, float4 each
  int e4 = idx & 255;                        // float4 index within row
  int r  = idx >> 8;                         // row 0..2047
  float4 v = ((const float4*)q)[idx];
  float xs[4] = {v.x, v.y, v.z, v.w};
  ushort4 hi, lo;
  unsigned short hb; float lf;
  hb = f2bf_rne(xs[0]); lf = xs[0]-bf2f(hb); hi.x = hb; lo.x = f2bf_rne(lf);
  hb = f2bf_rne(xs[1]); lf = xs[1]-bf2f(hb); hi.y = hb; lo.y = f2bf_rne(lf);
  hb = f2bf_rne(xs[2]); lf = xs[2]-bf2f(hb); hi.z = hb; lo.z = f2bf_rne(lf);
  hb = f2bf_rne(xs[3]); lf = xs[3]-bf2f(hb); hi.w = hb; lo.w = f2bf_rne(lf);
  *(ushort4*)&Aq[(size_t)r*2048 + e4*4]        = hi;
  *(ushort4*)&Aq[(size_t)r*2048 + 1024 + e4*4] = lo;
}

// -------- kD: transpose + split Wq/Wp into B'T (N x [hi|lo]) --------
__global__ __launch_bounds__(256) void kD_splitW(
    const float* __restrict__ Wq, const float* __restrict__ Wp,
    unsigned short* __restrict__ Btq, unsigned short* __restrict__ Btp) {
  __shared__ float tile[32][33];
  const float* W = blockIdx.z ? Wp : Wq;
  unsigned short* Bt = blockIdx.z ? Btp : Btq;
  int nt = blockIdx.x, kt = blockIdx.y;
  int t = threadIdx.x;
  int lr = t >> 3;            // 0..31
  int lc = (t & 7) * 4;       // 0..28
  float4 v = *(const float4*)&W[(size_t)(kt*32 + lr)*E_ + nt*32 + lc];
  tile[lr][lc+0] = v.x; tile[lr][lc+1] = v.y;
  tile[lr][lc+2] = v.z; tile[lr][lc+3] = v.w;
  __syncthreads();
  int n = nt*32 + lr;
  ushort4 hi, lo;
  unsigned short hb; float lf; float x;
  x = tile[lc+0][lr]; hb = f2bf_rne(x); lf = x-bf2f(hb); hi.x = hb; lo.x = f2bf_rne(lf);
  x = tile[lc+1][lr]; hb = f2bf_rne(x); lf = x-bf2f(hb); hi.y = hb; lo.y = f2bf_rne(lf);
  x = tile[lc+2][lr]; hb = f2bf_rne(x); lf = x-bf2f(hb); hi.z = hb; lo.z = f2bf_rne(lf);
  x = tile[lc+3][lr]; hb = f2bf_rne(x); lf = x-bf2f(hb); hi.w = hb; lo.w = f2bf_rne(lf);
  *(ushort4*)&Bt[(size_t)n*2048 + kt*32 + lc]        = hi;
  *(ushort4*)&Bt[(size_t)n*2048 + 1024 + kt*32 + lc] = lo;
}

// ---------------- k1: partial column sums of key and value ----------------
__global__ __launch_bounds__(256) void k1_colsum_partial(
    const float* __restrict__ key, const float* __restrict__ value,
    float* __restrict__ pk, float* __restrict__ pv) {
  int idx = blockIdx.x*256 + threadIdx.x;
  int e = idx % E_;
  int c = (idx / E_) % CHUNKS;
  int b = idx / (E_*CHUNKS);
  const float* kp = key   + ((size_t)(b*S_ + c*CHLEN))*E_ + e;
  const float* vp = value + ((size_t)(b*S_ + c*CHLEN))*E_ + e;
  float sk = 0.f, sv = 0.f;
  #pragma unroll
  for (int s = 0; s < CHLEN; ++s) {
    sk += kp[(size_t)s*E_];
    sv += vp[(size_t)s*E_];
  }
  pk[(b*CHUNKS + c)*E_ + e] = sk;
  pv[(b*CHUNKS + c)*E_ + e] = sv;
}

// ---------------- k2: ksum/vsum = colsum @ W + S*bias ----------------
__global__ __launch_bounds__(256) void k2_small_gemm(
    const float* __restrict__ pk, const float* __restrict__ pv,
    const float* __restrict__ Wk, const float* __restrict__ bk,
    const float* __restrict__ Wv, const float* __restrict__ bv,
    float* __restrict__ ksum, float* __restrict__ vsum) {
  __shared__ float colsum[E_];
  __shared__ float red[4][64];
  int bi = blockIdx.x;
  int j  = bi >> 5;
  int b  = (bi >> 4) & 1;
  int nt = bi & 15;
  int t = threadIdx.x;
  const float* p    = j ? pv : pk;
  const float* W    = j ? Wv : Wk;
  const float* bias = j ? bv : bk;
  float* out        = j ? vsum : ksum;
  for (int i = t; i < E_; i += 256) {
    float s = 0.f;
    #pragma unroll 8
    for (int c = 0; c < CHUNKS; ++c) s += p[(b*CHUNKS + c)*E_ + i];
    colsum[i] = s;
  }
  __syncthreads();
  int tx = t & 63, ty = t >> 6;
  int n = nt*64 + tx;
  float partial = 0.f;
  #pragma unroll 4
  for (int e = ty*256; e < ty*256 + 256; ++e)
    partial += colsum[e] * W[(size_t)e*E_ + n];
  red[ty][tx] = partial;
  __syncthreads();
  if (ty == 0) {
    out[b*E_ + n] = red[0][tx] + red[1][tx] + red[2][tx] + red[3][tx]
                  + (float)S_ * bias[n];
  }
}

// ---------------- k3: WV[b,h,n] = vsum[b,h*64+d] dot Wo ----------------
__global__ __launch_bounds__(256) void k3_wv(
    const float* __restrict__ vsum, const float* __restrict__ Wo,
    float* __restrict__ WV) {
  int idx = blockIdx.x*256 + threadIdx.x;
  int n = idx % E_;
  int h = (idx / E_) % H_;
  int b = idx / (E_*H_);
  float acc = 0.f;
  #pragma unroll 8
  for (int d = 0; d < HD_; ++d)
    acc += vsum[b*E_ + h*HD_ + d] * Wo[(size_t)(h*HD_ + d)*E_ + n];
  WV[idx] = acc;
}

// ---------------- kG: split-bf16 MFMA GEMM, K=3072 virtual ----------------
// z=0: Cq = query @ Wq + bq  (fp32-class accuracy via hi/lo 3-product)
// z=1: Cp = prefix(pos) @ Wp  (= Rpre directly)
// BM=128, BN=64, BK=64; 256 thr (4 waves 2x2); dbuf LDS 48KB; 2 blocks/CU.
#define GNT 48
__global__ __launch_bounds__(256, 2) void kG_gemm(
    const unsigned short* __restrict__ Aq, const unsigned short* __restrict__ Btq,
    const float* __restrict__ bq,
    const unsigned short* __restrict__ Ap, const unsigned short* __restrict__ Btp,
    float* __restrict__ Cq, float* __restrict__ Cp) {
  __shared__ __align__(128) char lds[49152];  // A: 2x16KB @0, B: 2x8KB @32768
  const int t = threadIdx.x;
  const int lane = t & 63;
  const int wm = (t >> 6) >> 1;   // 0..1
  const int wn = (t >> 6) & 1;    // 0..1
  const int bn = blockIdx.x, bm = blockIdx.y;

  const unsigned short* A; const unsigned short* Bt;
  const float* bias; float* C;
  if (blockIdx.z == 0) { A = Aq; Bt = Btq; bias = bq;      C = Cq; }
  else                 { A = Ap; Bt = Btp; bias = nullptr; C = Cp; }

  // Pre-swizzled global source addresses (rule 21: linear LDS dest,
  // inverse-swizzled source, swizzled read).
  const unsigned short* asrc[4];
  const unsigned short* bsrc[2];
  #pragma unroll
  for (int i = 0; i < 4; ++i) {
    int L = i*4096 + t*16;
    int row = L >> 7, bir = L & 127;
    int sw = bir ^ ((row & 7) << 4);
    asrc[i] = A + (size_t)(bm*128 + row)*2048 + (sw >> 1);
  }
  #pragma unroll
  for (int i = 0; i < 2; ++i) {
    int L = i*4096 + t*16;
    int row = L >> 7, bir = L & 127;
    int sw = bir ^ ((row & 7) << 4);
    bsrc[i] = Bt + (size_t)(bn*64 + row)*2048 + (sw >> 1);
  }
  // ds_read byte offsets (swizzled)
  int aoff[2][4], boff[2][2];
  #pragma unroll
  for (int ks = 0; ks < 2; ++ks) {
    int k0b = (ks*32 + (lane >> 4)*8) * 2;
    #pragma unroll
    for (int mi = 0; mi < 4; ++mi) {
      int row = wm*64 + mi*16 + (lane & 15);
      aoff[ks][mi] = row*128 + (k0b ^ ((row & 7) << 4));
    }
    #pragma unroll
    for (int ni = 0; ni < 2; ++ni) {
      int rown = wn*32 + ni*16 + (lane & 15);
      boff[ks][ni] = rown*128 + (k0b ^ ((rown & 7) << 4));
    }
  }

  f32x4 acc[4][2] = {};

  auto stage = [&](int buf, int kt) {
    int ak = (kt < 32) ? kt : kt - 32;   // A k-block: [hi | lo | hi]
    int bk = (kt < 16) ? kt : kt - 16;   // B k-block: [hi | hi | lo]
    char* Ab = lds + buf*16384;
    char* Bb = lds + 32768 + buf*8192;
    #pragma unroll
    for (int i = 0; i < 4; ++i)
      gload_lds16(asrc[i] + ak*64, Ab + i*4096 + t*16);
    #pragma unroll
    for (int i = 0; i < 2; ++i)
      gload_lds16(bsrc[i] + bk*64, Bb + i*4096 + t*16);
  };

  stage(0, 0);
  __syncthreads();
  int cur = 0;
  for (int kt = 0; kt < GNT; ++kt) {
    if (kt + 1 < GNT) stage(cur ^ 1, kt + 1);
    const char* Ab = lds + cur*16384;
    const char* Bb = lds + 32768 + cur*8192;
    bf16x8 af[2][4], bf_[2][2];
    #pragma unroll
    for (int ks = 0; ks < 2; ++ks) {
      #pragma unroll
      for (int mi = 0; mi < 4; ++mi)
        af[ks][mi] = *(const bf16x8*)(Ab + aoff[ks][mi]);
      #pragma unroll
      for (int ni = 0; ni < 2; ++ni)
        bf_[ks][ni] = *(const bf16x8*)(Bb + boff[ks][ni]);
    }
    #pragma unroll
    for (int ks = 0; ks < 2; ++ks)
      #pragma unroll
      for (int mi = 0; mi < 4; ++mi)
        #pragma unroll
        for (int ni = 0; ni < 2; ++ni)
          acc[mi][ni] = __builtin_amdgcn_mfma_f32_16x16x32_bf16(
              af[ks][mi], bf_[ks][ni], acc[mi][ni], 0, 0, 0);
    __syncthreads();
    cur ^= 1;
  }

  // Epilogue: C/D layout col=lane&15, row=(lane>>4)*4+j
  #pragma unroll
  for (int mi = 0; mi < 4; ++mi) {
    #pragma unroll
    for (int ni = 0; ni < 2; ++ni) {
      int col  = bn*64 + wn*32 + ni*16 + (lane & 15);
      int row0 = bm*128 + wm*64 + mi*16 + (lane >> 4)*4;
      float badd = bias ? bias[col] : 0.f;
      #pragma unroll
      for (int j = 0; j < 4; ++j)
        C[(size_t)(row0 + j)*E_ + col] = acc[mi][ni][j] + badd;
    }
  }
}

// ---------------- k6: score row-sums via prefix algebra ----------------
__global__ __launch_bounds__(256) void k6_rs(
    const float* __restrict__ qp, const float* __restrict__ Rpre,
    const float* __restrict__ ksum, const float* __restrict__ U,
    const float* __restrict__ V, float* __restrict__ rs) {
  int w    = blockIdx.x*4 + (threadIdx.x >> 6);
  int lane = threadIdx.x & 63;
  int q = w % S_;
  int h = (w / S_) % H_;
  int b = w / (S_*H_);
  int he = h*HD_ + lane;
  float qv0  = qp[((size_t)(b*S_ + q))*E_ + he];
  float u    = U[he], vv = V[he];
  float ks   = ksum[b*E_ + he];
  float rtot = Rpre[((size_t)(b*S_ + (S_-1)))*E_ + he];
  float tail = rtot;
  if (q <= S_-2) tail -= Rpre[((size_t)(b*S_ + (S_-2-q)))*E_ + he];
  float p = (qv0 + u)*ks + (qv0 + vv)*tail;
  if (q <= S_-3) {
    float qv1 = qp[((size_t)(b*S_ + q + 1))*E_ + he];
    float hd  = Rpre[((size_t)(b*S_ + (S_-3-q)))*E_ + he];
    p += (qv1 + vv)*hd;
  }
  #pragma unroll
  for (int off = 32; off >= 1; off >>= 1)
    p += __shfl_xor(p, off);
  if (lane == 0) rs[(b*H_ + h)*S_ + q] = p * SCALE;
}

// ---------------- k7: out = rs x WV + bo ----------------
__global__ __launch_bounds__(256) void k7_out(
    const float* __restrict__ rs, const float* __restrict__ WV,
    const float* __restrict__ bo, float* __restrict__ out) {
  int idx = blockIdx.x*256 + threadIdx.x;
  int n = idx % E_;
  int q = (idx / E_) % S_;
  int b = idx / (E_*S_);
  float acc = bo[n];
  #pragma unroll
  for (int h = 0; h < H_; ++h)
    acc += rs[(b*H_ + h)*S_ + q] * WV[((size_t)(b*H_ + h))*E_ + n];
  out[idx] = acc;
}

extern "C" void kernel_launch(void* const* d_in, const int* in_sizes, int n_in,
                              void* d_out, int out_size, void* d_ws, size_t ws_size,
                              hipStream_t stream) {
  const float* query = (const float*)d_in[0];
  const float* key   = (const float*)d_in[1];
  const float* value = (const float*)d_in[2];
  const float* pos   = (const float*)d_in[3];
  const float* Wq = (const float*)d_in[4];
  const float* bq = (const float*)d_in[5];
  const float* Wk = (const float*)d_in[6];
  const float* bk = (const float*)d_in[7];
  const float* Wv = (const float*)d_in[8];
  const float* bv = (const float*)d_in[9];
  const float* Wp = (const float*)d_in[10];
  const float* U  = (const float*)d_in[11];
  const float* V  = (const float*)d_in[12];
  const float* Wo = (const float*)d_in[13];
  const float* bo = (const float*)d_in[14];
  float* out = (float*)d_out;
  char* wsb = (char*)d_ws;

  // Compact layout, peak ~34 MB (qproj lives in d_out until k7 overwrites it).
  unsigned short* Aqs = (unsigned short*)(wsb);                       // 8 MB
  unsigned short* Aps = (unsigned short*)(wsb + (8ull<<20));          // 8 MB
  unsigned short* Btq = (unsigned short*)(wsb + (16ull<<20));         // 4 MB
  unsigned short* Btp = (unsigned short*)(wsb + (20ull<<20));         // 4 MB
  float* Rpre  = (float*)(wsb + (24ull<<20));                         // 8 MB
  char*  smallb = wsb + (32ull<<20);
  float* seg   = (float*)(smallb);                                    // 512 KB
  float* pk    = (float*)(smallb + (512ull<<10));                     // 512 KB
  float* pv    = (float*)(smallb + (1024ull<<10));                    // 512 KB
  float* ksum  = (float*)(smallb + (1536ull<<10));                    // 8 KB
  float* vsum  = (float*)(smallb + (1544ull<<10));                    // 8 KB
  float* WVb   = (float*)(smallb + (1552ull<<10));                    // 128 KB
  float* rs    = (float*)(smallb + (1680ull<<10));                    // 128 KB
  float* qproj = out;   // consumed by k6 before k7 rewrites d_out

  hipLaunchKernelGGL(kA_segsum, dim3(B_*NSEG*E_/256), dim3(256), 0, stream, pos, seg);
  hipLaunchKernelGGL(kB_scan_split, dim3(B_*NSEG*E_/256), dim3(256), 0, stream, pos, seg, Aps);
  hipLaunchKernelGGL(kC_split_q, dim3(B_*S_*E_/4/256), dim3(256), 0, stream, query, Aqs);
  hipLaunchKernelGGL(kD_splitW, dim3(32, 32, 2), dim3(256), 0, stream, Wq, Wp, Btq, Btp);
  hipLaunchKernelGGL(k1_colsum_partial, dim3(B_*CHUNKS*E_/256), dim3(256), 0, stream,
                     key, value, pk, pv);
  hipLaunchKernelGGL(k2_small_gemm, dim3(64), dim3(256), 0, stream,
                     pk, pv, Wk, bk, Wv, bv, ksum, vsum);
  hipLaunchKernelGGL(k3_wv, dim3(B_*H_*E_/256), dim3(256), 0, stream, vsum, Wo, WVb);
  hipLaunchKernelGGL(kG_gemm, dim3(E_/64, B_*S_/128, 2), dim3(256), 0, stream,
                     Aqs, Btq, bq, Aps, Btp, qproj, Rpre);
  hipLaunchKernelGGL(k6_rs, dim3(B_*H_*S_/4), dim3(256), 0, stream,
                     qproj, Rpre, ksum, U, V, rs);
  hipLaunchKernelGGL(k7_out, dim3(B_*S_*E_/256), dim3(256), 0, stream,
                     rs, WVb, bo, out);
}

// Round 7
// 211.752 us; speedup vs baseline: 1.7528x; 1.1507x over previous
//
#include <hip/hip_runtime.h>
#include <cstddef>
#include <cstdint>

// Problem constants (fixed by setup_inputs).
#define E_ 1024
#define H_ 16
#define HD_ 64
#define B_ 2
#define S_ 1024
#define NSEG 64
#define SEGLEN (S_/NSEG)          // 16
#define CHUNKS 64
#define CHLEN (S_/CHUNKS)         // 16
#define SCALE 0.03125f            // 1/sqrt(E)

typedef __attribute__((ext_vector_type(8))) short bf16x8;
typedef __attribute__((ext_vector_type(4))) float f32x4;

__device__ __forceinline__ unsigned short f2bf_rne(float x) {
  uint32_t u = __float_as_uint(x);
  uint32_t r = u + 0x7FFFu + ((u >> 16) & 1u);
  return (unsigned short)(r >> 16);
}
__device__ __forceinline__ float bf2f(unsigned short h) {
  return __uint_as_float(((uint32_t)h) << 16);
}
__device__ __forceinline__ void gload_lds16(const void* g, void* l) {
  __builtin_amdgcn_global_load_lds(
      (const __attribute__((address_space(1))) void*)g,
      (__attribute__((address_space(3))) void*)l, 16, 0, 0);
}

// ---------------- kA: per-segment sums of pos (for scan) ----------------
__global__ __launch_bounds__(256) void kA_segsum(
    const float* __restrict__ pos, float* __restrict__ seg) {
  int idx = blockIdx.x*256 + threadIdx.x;
  int e = idx % E_;
  int g = (idx / E_) % NSEG;
  int b = idx / (E_*NSEG);
  const float* p = pos + ((size_t)(b*S_ + g*SEGLEN))*E_ + e;
  float s = 0.f;
  #pragma unroll
  for (int i = 0; i < SEGLEN; ++i) s += p[(size_t)i*E_];
  seg[(b*NSEG + g)*E_ + e] = s;
}

// ---- kB: inclusive prefix-scan of pos along s, fused split-bf16 write ----
// A'p layout: [2048 rows][2048]: cols [0,1024)=hi, [1024,2048)=lo
__global__ __launch_bounds__(256) void kB_scan_split(
    const float* __restrict__ pos, const float* __restrict__ seg,
    unsigned short* __restrict__ Ap) {
  int idx = blockIdx.x*256 + threadIdx.x;
  int e = idx % E_;
  int g = (idx / E_) % NSEG;
  int b = idx / (E_*NSEG);
  float run = 0.f;
  for (int gp = 0; gp < g; ++gp) run += seg[(b*NSEG + gp)*E_ + e];
  const float* p = pos + ((size_t)(b*S_ + g*SEGLEN))*E_ + e;
  #pragma unroll
  for (int i = 0; i < SEGLEN; ++i) {
    run += p[(size_t)i*E_];
    size_t row = (size_t)(b*S_ + g*SEGLEN + i);
    unsigned short hb = f2bf_rne(run);
    float lf = run - bf2f(hb);
    Ap[row*2048 + e]        = hb;
    Ap[row*2048 + 1024 + e] = f2bf_rne(lf);
  }
}

// ---------------- kC: split query into A'q (hi|lo) ----------------
__global__ __launch_bounds__(256) void kC_split_q(
    const float* __restrict__ q, unsigned short* __restrict__ Aq) {
  int idx = blockIdx.x*256 + threadIdx.x;   // 512K threads, float4 each
  int e4 = idx & 255;                        // float4 index within row
  int r  = idx >> 8;                         // row 0..2047
  float4 v = ((const float4*)q)[idx];
  float xs[4] = {v.x, v.y, v.z, v.w};
  ushort4 hi, lo;
  unsigned short hb; float lf;
  hb = f2bf_rne(xs[0]); lf = xs[0]-bf2f(hb); hi.x = hb; lo.x = f2bf_rne(lf);
  hb = f2bf_rne(xs[1]); lf = xs[1]-bf2f(hb); hi.y = hb; lo.y = f2bf_rne(lf);
  hb = f2bf_rne(xs[2]); lf = xs[2]-bf2f(hb); hi.z = hb; lo.z = f2bf_rne(lf);
  hb = f2bf_rne(xs[3]); lf = xs[3]-bf2f(hb); hi.w = hb; lo.w = f2bf_rne(lf);
  *(ushort4*)&Aq[(size_t)r*2048 + e4*4]        = hi;
  *(ushort4*)&Aq[(size_t)r*2048 + 1024 + e4*4] = lo;
}

// -------- kD: transpose + split Wq/Wp into B'T (N x [hi|lo]) --------
__global__ __launch_bounds__(256) void kD_splitW(
    const float* __restrict__ Wq, const float* __restrict__ Wp,
    unsigned short* __restrict__ Btq, unsigned short* __restrict__ Btp) {
  __shared__ float tile[32][33];
  const float* W = blockIdx.z ? Wp : Wq;
  unsigned short* Bt = blockIdx.z ? Btp : Btq;
  int nt = blockIdx.x, kt = blockIdx.y;
  int t = threadIdx.x;
  int lr = t >> 3;            // 0..31
  int lc = (t & 7) * 4;       // 0..28
  float4 v = *(const float4*)&W[(size_t)(kt*32 + lr)*E_ + nt*32 + lc];
  tile[lr][lc+0] = v.x; tile[lr][lc+1] = v.y;
  tile[lr][lc+2] = v.z; tile[lr][lc+3] = v.w;
  __syncthreads();
  int n = nt*32 + lr;
  ushort4 hi, lo;
  unsigned short hb; float lf; float x;
  x = tile[lc+0][lr]; hb = f2bf_rne(x); lf = x-bf2f(hb); hi.x = hb; lo.x = f2bf_rne(lf);
  x = tile[lc+1][lr]; hb = f2bf_rne(x); lf = x-bf2f(hb); hi.y = hb; lo.y = f2bf_rne(lf);
  x = tile[lc+2][lr]; hb = f2bf_rne(x); lf = x-bf2f(hb); hi.z = hb; lo.z = f2bf_rne(lf);
  x = tile[lc+3][lr]; hb = f2bf_rne(x); lf = x-bf2f(hb); hi.w = hb; lo.w = f2bf_rne(lf);
  *(ushort4*)&Bt[(size_t)n*2048 + kt*32 + lc]        = hi;
  *(ushort4*)&Bt[(size_t)n*2048 + 1024 + kt*32 + lc] = lo;
}

// ---------------- k1: partial column sums of key and value ----------------
__global__ __launch_bounds__(256) void k1_colsum_partial(
    const float* __restrict__ key, const float* __restrict__ value,
    float* __restrict__ pk, float* __restrict__ pv) {
  int idx = blockIdx.x*256 + threadIdx.x;
  int e = idx % E_;
  int c = (idx / E_) % CHUNKS;
  int b = idx / (E_*CHUNKS);
  const float* kp = key   + ((size_t)(b*S_ + c*CHLEN))*E_ + e;
  const float* vp = value + ((size_t)(b*S_ + c*CHLEN))*E_ + e;
  float sk = 0.f, sv = 0.f;
  #pragma unroll
  for (int s = 0; s < CHLEN; ++s) {
    sk += kp[(size_t)s*E_];
    sv += vp[(size_t)s*E_];
  }
  pk[(b*CHUNKS + c)*E_ + e] = sk;
  pv[(b*CHUNKS + c)*E_ + e] = sv;
}

// ------- k2a: colsum[j][b][e] = sum_c (j?pv:pk)[(b*CHUNKS+c)*E_+e] -------
__global__ __launch_bounds__(256) void k2a_colsum(
    const float* __restrict__ pk, const float* __restrict__ pv,
    float* __restrict__ colsum) {
  int idx = blockIdx.x*256 + threadIdx.x;  // 4096 threads
  int e = idx & 1023;
  int b = (idx >> 10) & 1;
  int j = idx >> 11;
  const float* p = j ? pv : pk;
  float s = 0.f;
  #pragma unroll 8
  for (int c = 0; c < CHUNKS; ++c) s += p[(b*CHUNKS + c)*E_ + e];
  colsum[idx] = s;
}

// -- k2b: partial[j][slice][b][n] = sum_{e in 64-row slice} cs*W, W row-major --
__global__ __launch_bounds__(256) void k2b_gemv(
    const float* __restrict__ colsum, const float* __restrict__ Wk,
    const float* __restrict__ Wv, float* __restrict__ partial) {
  int j     = blockIdx.z;                  // 0..1 (k / v)
  int slice = blockIdx.y;                  // 0..15
  int n     = blockIdx.x*256 + threadIdx.x;
  const float* W  = j ? Wv : Wk;
  const float* cs = colsum + j*2048;
  float a0 = 0.f, a1 = 0.f;
  int e0 = slice*64;
  #pragma unroll 8
  for (int i = 0; i < 64; ++i) {
    int e = e0 + i;
    float w = W[(size_t)e*E_ + n];
    a0 += cs[e] * w;
    a1 += cs[1024 + e] * w;
  }
  partial[(size_t)((j*16 + slice)*2 + 0)*E_ + n] = a0;
  partial[(size_t)((j*16 + slice)*2 + 1)*E_ + n] = a1;
}

// ------ k2c: ksum/vsum[b][n] = sum_slice partial + S*bias ------
__global__ __launch_bounds__(256) void k2c_reduce(
    const float* __restrict__ partial, const float* __restrict__ bk,
    const float* __restrict__ bv, float* __restrict__ ksum,
    float* __restrict__ vsum) {
  int idx = blockIdx.x*256 + threadIdx.x;  // 4096 threads
  int n = idx & 1023;
  int b = (idx >> 10) & 1;
  int j = idx >> 11;
  const float* base = partial + (size_t)(j*32 + b)*E_ + n;
  float s = 0.f;
  #pragma unroll
  for (int sl = 0; sl < 16; ++sl) s += base[(size_t)sl*2*E_];
  s += (float)S_ * (j ? bv[n] : bk[n]);
  (j ? vsum : ksum)[b*E_ + n] = s;
}

// ---------------- k3: WV[b,h,n] = vsum[b,h*64+d] dot Wo ----------------
__global__ __launch_bounds__(256) void k3_wv(
    const float* __restrict__ vsum, const float* __restrict__ Wo,
    float* __restrict__ WV) {
  int idx = blockIdx.x*256 + threadIdx.x;
  int n = idx % E_;
  int h = (idx / E_) % H_;
  int b = idx / (E_*H_);
  float acc = 0.f;
  #pragma unroll 8
  for (int d = 0; d < HD_; ++d)
    acc += vsum[b*E_ + h*HD_ + d] * Wo[(size_t)(h*HD_ + d)*E_ + n];
  WV[idx] = acc;
}

// ---------------- kG: split-bf16 MFMA GEMM, K=3072 virtual ----------------
// z=0: Cq = query @ Wq + bq  (fp32-class accuracy via hi/lo 3-product)
// z=1: Cp = prefix(pos) @ Wp  (= Rpre directly)
// BM=128, BN=64, BK=64; 256 thr (4 waves 2x2); dbuf LDS 48KB; 2 blocks/CU.
#define GNT 48
__global__ __launch_bounds__(256, 2) void kG_gemm(
    const unsigned short* __restrict__ Aq, const unsigned short* __restrict__ Btq,
    const float* __restrict__ bq,
    const unsigned short* __restrict__ Ap, const unsigned short* __restrict__ Btp,
    float* __restrict__ Cq, float* __restrict__ Cp) {
  __shared__ __align__(128) char lds[49152];  // A: 2x16KB @0, B: 2x8KB @32768
  const int t = threadIdx.x;
  const int lane = t & 63;
  const int wm = (t >> 6) >> 1;   // 0..1
  const int wn = (t >> 6) & 1;    // 0..1
  const int bn = blockIdx.x, bm = blockIdx.y;

  const unsigned short* A; const unsigned short* Bt;
  const float* bias; float* C;
  if (blockIdx.z == 0) { A = Aq; Bt = Btq; bias = bq;      C = Cq; }
  else                 { A = Ap; Bt = Btp; bias = nullptr; C = Cp; }

  // Pre-swizzled global source addresses (rule 21: linear LDS dest,
  // inverse-swizzled source, swizzled read).
  const unsigned short* asrc[4];
  const unsigned short* bsrc[2];
  #pragma unroll
  for (int i = 0; i < 4; ++i) {
    int L = i*4096 + t*16;
    int row = L >> 7, bir = L & 127;
    int sw = bir ^ ((row & 7) << 4);
    asrc[i] = A + (size_t)(bm*128 + row)*2048 + (sw >> 1);
  }
  #pragma unroll
  for (int i = 0; i < 2; ++i) {
    int L = i*4096 + t*16;
    int row = L >> 7, bir = L & 127;
    int sw = bir ^ ((row & 7) << 4);
    bsrc[i] = Bt + (size_t)(bn*64 + row)*2048 + (sw >> 1);
  }
  // ds_read byte offsets (swizzled)
  int aoff[2][4], boff[2][2];
  #pragma unroll
  for (int ks = 0; ks < 2; ++ks) {
    int k0b = (ks*32 + (lane >> 4)*8) * 2;
    #pragma unroll
    for (int mi = 0; mi < 4; ++mi) {
      int row = wm*64 + mi*16 + (lane & 15);
      aoff[ks][mi] = row*128 + (k0b ^ ((row & 7) << 4));
    }
    #pragma unroll
    for (int ni = 0; ni < 2; ++ni) {
      int rown = wn*32 + ni*16 + (lane & 15);
      boff[ks][ni] = rown*128 + (k0b ^ ((rown & 7) << 4));
    }
  }

  f32x4 acc[4][2] = {};

  auto stage = [&](int buf, int kt) {
    int ak = (kt < 32) ? kt : kt - 32;   // A k-block: [hi | lo | hi]
    int bk = (kt < 16) ? kt : kt - 16;   // B k-block: [hi | hi | lo]
    char* Ab = lds + buf*16384;
    char* Bb = lds + 32768 + buf*8192;
    #pragma unroll
    for (int i = 0; i < 4; ++i)
      gload_lds16(asrc[i] + ak*64, Ab + i*4096 + t*16);
    #pragma unroll
    for (int i = 0; i < 2; ++i)
      gload_lds16(bsrc[i] + bk*64, Bb + i*4096 + t*16);
  };

  stage(0, 0);
  __syncthreads();
  int cur = 0;
  for (int kt = 0; kt < GNT; ++kt) {
    if (kt + 1 < GNT) stage(cur ^ 1, kt + 1);
    const char* Ab = lds + cur*16384;
    const char* Bb = lds + 32768 + cur*8192;
    bf16x8 af[2][4], bf_[2][2];
    #pragma unroll
    for (int ks = 0; ks < 2; ++ks) {
      #pragma unroll
      for (int mi = 0; mi < 4; ++mi)
        af[ks][mi] = *(const bf16x8*)(Ab + aoff[ks][mi]);
      #pragma unroll
      for (int ni = 0; ni < 2; ++ni)
        bf_[ks][ni] = *(const bf16x8*)(Bb + boff[ks][ni]);
    }
    #pragma unroll
    for (int ks = 0; ks < 2; ++ks)
      #pragma unroll
      for (int mi = 0; mi < 4; ++mi)
        #pragma unroll
        for (int ni = 0; ni < 2; ++ni)
          acc[mi][ni] = __builtin_amdgcn_mfma_f32_16x16x32_bf16(
              af[ks][mi], bf_[ks][ni], acc[mi][ni], 0, 0, 0);
    __syncthreads();
    cur ^= 1;
  }

  // Epilogue: C/D layout col=lane&15, row=(lane>>4)*4+j
  #pragma unroll
  for (int mi = 0; mi < 4; ++mi) {
    #pragma unroll
    for (int ni = 0; ni < 2; ++ni) {
      int col  = bn*64 + wn*32 + ni*16 + (lane & 15);
      int row0 = bm*128 + wm*64 + mi*16 + (lane >> 4)*4;
      float badd = bias ? bias[col] : 0.f;
      #pragma unroll
      for (int j = 0; j < 4; ++j)
        C[(size_t)(row0 + j)*E_ + col] = acc[mi][ni][j] + badd;
    }
  }
}

// ---------------- k6: score row-sums via prefix algebra ----------------
__global__ __launch_bounds__(256) void k6_rs(
    const float* __restrict__ qp, const float* __restrict__ Rpre,
    const float* __restrict__ ksum, const float* __restrict__ U,
    const float* __restrict__ V, float* __restrict__ rs) {
  int w    = blockIdx.x*4 + (threadIdx.x >> 6);
  int lane = threadIdx.x & 63;
  int q = w % S_;
  int h = (w / S_) % H_;
  int b = w / (S_*H_);
  int he = h*HD_ + lane;
  float qv0  = qp[((size_t)(b*S_ + q))*E_ + he];
  float u    = U[he], vv = V[he];
  float ks   = ksum[b*E_ + he];
  float rtot = Rpre[((size_t)(b*S_ + (S_-1)))*E_ + he];
  float tail = rtot;
  if (q <= S_-2) tail -= Rpre[((size_t)(b*S_ + (S_-2-q)))*E_ + he];
  float p = (qv0 + u)*ks + (qv0 + vv)*tail;
  if (q <= S_-3) {
    float qv1 = qp[((size_t)(b*S_ + q + 1))*E_ + he];
    float hd  = Rpre[((size_t)(b*S_ + (S_-3-q)))*E_ + he];
    p += (qv1 + vv)*hd;
  }
  #pragma unroll
  for (int off = 32; off >= 1; off >>= 1)
    p += __shfl_xor(p, off);
  if (lane == 0) rs[(b*H_ + h)*S_ + q] = p * SCALE;
}

// ---------------- k7: out = rs x WV + bo ----------------
__global__ __launch_bounds__(256) void k7_out(
    const float* __restrict__ rs, const float* __restrict__ WV,
    const float* __restrict__ bo, float* __restrict__ out) {
  int idx = blockIdx.x*256 + threadIdx.x;
  int n = idx % E_;
  int q = (idx / E_) % S_;
  int b = idx / (E_*S_);
  float acc = bo[n];
  #pragma unroll
  for (int h = 0; h < H_; ++h)
    acc += rs[(b*H_ + h)*S_ + q] * WV[((size_t)(b*H_ + h))*E_ + n];
  out[idx] = acc;
}

extern "C" void kernel_launch(void* const* d_in, const int* in_sizes, int n_in,
                              void* d_out, int out_size, void* d_ws, size_t ws_size,
                              hipStream_t stream) {
  const float* query = (const float*)d_in[0];
  const float* key   = (const float*)d_in[1];
  const float* value = (const float*)d_in[2];
  const float* pos   = (const float*)d_in[3];
  const float* Wq = (const float*)d_in[4];
  const float* bq = (const float*)d_in[5];
  const float* Wk = (const float*)d_in[6];
  const float* bk = (const float*)d_in[7];
  const float* Wv = (const float*)d_in[8];
  const float* bv = (const float*)d_in[9];
  const float* Wp = (const float*)d_in[10];
  const float* U  = (const float*)d_in[11];
  const float* V  = (const float*)d_in[12];
  const float* Wo = (const float*)d_in[13];
  const float* bo = (const float*)d_in[14];
  float* out = (float*)d_out;
  char* wsb = (char*)d_ws;

  // Compact layout, peak ~34 MB (qproj lives in d_out until k7 overwrites it).
  unsigned short* Aqs = (unsigned short*)(wsb);                       // 8 MB
  unsigned short* Aps = (unsigned short*)(wsb + (8ull<<20));          // 8 MB
  unsigned short* Btq = (unsigned short*)(wsb + (16ull<<20));         // 4 MB
  unsigned short* Btp = (unsigned short*)(wsb + (20ull<<20));         // 4 MB
  float* Rpre  = (float*)(wsb + (24ull<<20));                         // 8 MB
  char*  smallb = wsb + (32ull<<20);
  float* seg   = (float*)(smallb);                                    // 512 KB
  float* pk    = (float*)(smallb + (512ull<<10));                     // 512 KB
  float* pv    = (float*)(smallb + (1024ull<<10));                    // 512 KB
  float* ksum  = (float*)(smallb + (1536ull<<10));                    // 8 KB
  float* vsum  = (float*)(smallb + (1544ull<<10));                    // 8 KB
  float* WVb   = (float*)(smallb + (1552ull<<10));                    // 128 KB
  float* rs    = (float*)(smallb + (1680ull<<10));                    // 128 KB
  float* qproj = out;   // consumed by k6 before k7 rewrites d_out
  // seg is dead after kB -> reuse its 512 KB for the k2 pipeline scratch.
  float* colsum  = seg;                      // 16 KB  (2j x 2b x 1024)
  float* partial = seg + 4096;               // 256 KB (2j x 16sl x 2b x 1024)

  hipLaunchKernelGGL(kA_segsum, dim3(B_*NSEG*E_/256), dim3(256), 0, stream, pos, seg);
  hipLaunchKernelGGL(kB_scan_split, dim3(B_*NSEG*E_/256), dim3(256), 0, stream, pos, seg, Aps);
  hipLaunchKernelGGL(kC_split_q, dim3(B_*S_*E_/4/256), dim3(256), 0, stream, query, Aqs);
  hipLaunchKernelGGL(kD_splitW, dim3(32, 32, 2), dim3(256), 0, stream, Wq, Wp, Btq, Btp);
  hipLaunchKernelGGL(k1_colsum_partial, dim3(B_*CHUNKS*E_/256), dim3(256), 0, stream,
                     key, value, pk, pv);
  hipLaunchKernelGGL(k2a_colsum, dim3(16), dim3(256), 0, stream, pk, pv, colsum);
  hipLaunchKernelGGL(k2b_gemv, dim3(4, 16, 2), dim3(256), 0, stream,
                     colsum, Wk, Wv, partial);
  hipLaunchKernelGGL(k2c_reduce, dim3(16), dim3(256), 0, stream,
                     partial, bk, bv, ksum, vsum);
  hipLaunchKernelGGL(k3_wv, dim3(B_*H_*E_/256), dim3(256), 0, stream, vsum, Wo, WVb);
  hipLaunchKernelGGL(kG_gemm, dim3(E_/64, B_*S_/128, 2), dim3(256), 0, stream,
                     Aqs, Btq, bq, Aps, Btp, qproj, Rpre);
  hipLaunchKernelGGL(k6_rs, dim3(B_*H_*S_/4), dim3(256), 0, stream,
                     qproj, Rpre, ksum, U, V, rs);
  hipLaunchKernelGGL(k7_out, dim3(B_*S_*E_/256), dim3(256), 0, stream,
                     rs, WVb, bo, out);
}

// Round 10
// 191.476 us; speedup vs baseline: 1.9384x; 1.1059x over previous
//
#include <hip/hip_runtime.h>
#include <cstddef>
#include <cstdint>

// Problem constants (fixed by setup_inputs).
#define E_ 1024
#define H_ 16
#define HD_ 64
#define B_ 2
#define S_ 1024
#define NSEG 64
#define SEGLEN (S_/NSEG)          // 16
#define CHUNKS 64
#define CHLEN (S_/CHUNKS)         // 16
#define SCALE 0.03125f            // 1/sqrt(E)

typedef __attribute__((ext_vector_type(8))) short bf16x8;
typedef __attribute__((ext_vector_type(4))) float f32x4;

__device__ __forceinline__ unsigned short f2bf_rne(float x) {
  uint32_t u = __float_as_uint(x);
  uint32_t r = u + 0x7FFFu + ((u >> 16) & 1u);
  return (unsigned short)(r >> 16);
}
__device__ __forceinline__ float bf2f(unsigned short h) {
  return __uint_as_float(((uint32_t)h) << 16);
}
__device__ __forceinline__ void gload_lds16(const void* g, void* l) {
  __builtin_amdgcn_global_load_lds(
      (const __attribute__((address_space(1))) void*)g,
      (__attribute__((address_space(3))) void*)l, 16, 0, 0);
}

// ================= P1: independent prep (kA | kC | kD | k1) =================
// blocks [0,512): kA_segsum   [512,2560): kC_split_q
// [2560,4608): kD_splitW      [4608,5120): k1_colsum
__global__ __launch_bounds__(256) void kP1(
    const float* __restrict__ query, const float* __restrict__ pos,
    const float* __restrict__ key,   const float* __restrict__ value,
    const float* __restrict__ Wq,    const float* __restrict__ Wp,
    float* __restrict__ seg, unsigned short* __restrict__ Aq,
    float* __restrict__ pk, float* __restrict__ pv,
    unsigned short* __restrict__ Btq, unsigned short* __restrict__ Btp) {
  __shared__ float tile[32][33];
  int bid = blockIdx.x;
  int t = threadIdx.x;
  if (bid < 512) {
    // ---- kA: per-segment sums of pos ----
    int idx = bid*256 + t;
    int e = idx % E_;
    int g = (idx / E_) % NSEG;
    int b = idx / (E_*NSEG);
    const float* p = pos + ((size_t)(b*S_ + g*SEGLEN))*E_ + e;
    float s = 0.f;
    #pragma unroll
    for (int i = 0; i < SEGLEN; ++i) s += p[(size_t)i*E_];
    seg[(b*NSEG + g)*E_ + e] = s;
  } else if (bid < 2560) {
    // ---- kC: split query into A'q (hi|lo) ----
    int idx = (bid-512)*256 + t;
    int e4 = idx & 255;
    int r  = idx >> 8;
    float4 v = ((const float4*)query)[idx];
    float xs[4] = {v.x, v.y, v.z, v.w};
    ushort4 hi, lo;
    unsigned short hb; float lf;
    hb = f2bf_rne(xs[0]); lf = xs[0]-bf2f(hb); hi.x = hb; lo.x = f2bf_rne(lf);
    hb = f2bf_rne(xs[1]); lf = xs[1]-bf2f(hb); hi.y = hb; lo.y = f2bf_rne(lf);
    hb = f2bf_rne(xs[2]); lf = xs[2]-bf2f(hb); hi.z = hb; lo.z = f2bf_rne(lf);
    hb = f2bf_rne(xs[3]); lf = xs[3]-bf2f(hb); hi.w = hb; lo.w = f2bf_rne(lf);
    *(ushort4*)&Aq[(size_t)r*2048 + e4*4]        = hi;
    *(ushort4*)&Aq[(size_t)r*2048 + 1024 + e4*4] = lo;
  } else if (bid < 4608) {
    // ---- kD: transpose + split Wq/Wp into B'T ----
    int f = bid - 2560;
    int nt = f & 31, kt = (f >> 5) & 31, z = f >> 10;
    const float* W = z ? Wp : Wq;
    unsigned short* Bt = z ? Btp : Btq;
    int lr = t >> 3;
    int lc = (t & 7) * 4;
    float4 v = *(const float4*)&W[(size_t)(kt*32 + lr)*E_ + nt*32 + lc];
    tile[lr][lc+0] = v.x; tile[lr][lc+1] = v.y;
    tile[lr][lc+2] = v.z; tile[lr][lc+3] = v.w;
    __syncthreads();
    int n = nt*32 + lr;
    ushort4 hi, lo;
    unsigned short hb; float lf; float x;
    x = tile[lc+0][lr]; hb = f2bf_rne(x); lf = x-bf2f(hb); hi.x = hb; lo.x = f2bf_rne(lf);
    x = tile[lc+1][lr]; hb = f2bf_rne(x); lf = x-bf2f(hb); hi.y = hb; lo.y = f2bf_rne(lf);
    x = tile[lc+2][lr]; hb = f2bf_rne(x); lf = x-bf2f(hb); hi.z = hb; lo.z = f2bf_rne(lf);
    x = tile[lc+3][lr]; hb = f2bf_rne(x); lf = x-bf2f(hb); hi.w = hb; lo.w = f2bf_rne(lf);
    *(ushort4*)&Bt[(size_t)n*2048 + kt*32 + lc]        = hi;
    *(ushort4*)&Bt[(size_t)n*2048 + 1024 + kt*32 + lc] = lo;
  } else {
    // ---- k1: partial column sums of key and value ----
    int idx = (bid-4608)*256 + t;
    int e = idx % E_;
    int c = (idx / E_) % CHUNKS;
    int b = idx / (E_*CHUNKS);
    const float* kp = key   + ((size_t)(b*S_ + c*CHLEN))*E_ + e;
    const float* vp = value + ((size_t)(b*S_ + c*CHLEN))*E_ + e;
    float sk = 0.f, sv = 0.f;
    #pragma unroll
    for (int s = 0; s < CHLEN; ++s) {
      sk += kp[(size_t)s*E_];
      sv += vp[(size_t)s*E_];
    }
    pk[(b*CHUNKS + c)*E_ + e] = sk;
    pv[(b*CHUNKS + c)*E_ + e] = sv;
  }
}

// ============ P2: kB scan+split | k2a colsum + ksum/vsum init ============
// blocks [0,512): kB   [512,528): k2a + init
__global__ __launch_bounds__(256) void kP2(
    const float* __restrict__ pos, const float* __restrict__ seg,
    unsigned short* __restrict__ Ap,
    const float* __restrict__ pk, const float* __restrict__ pv,
    const float* __restrict__ bk, const float* __restrict__ bv,
    float* __restrict__ colsum, float* __restrict__ ksum,
    float* __restrict__ vsum) {
  int bid = blockIdx.x;
  int t = threadIdx.x;
  if (bid < 512) {
    // ---- kB: inclusive prefix-scan of pos, fused split-bf16 write ----
    int idx = bid*256 + t;
    int e = idx % E_;
    int g = (idx / E_) % NSEG;
    int b = idx / (E_*NSEG);
    float run = 0.f;
    for (int gp = 0; gp < g; ++gp) run += seg[(b*NSEG + gp)*E_ + e];
    const float* p = pos + ((size_t)(b*S_ + g*SEGLEN))*E_ + e;
    #pragma unroll
    for (int i = 0; i < SEGLEN; ++i) {
      run += p[(size_t)i*E_];
      size_t row = (size_t)(b*S_ + g*SEGLEN + i);
      unsigned short hb = f2bf_rne(run);
      float lf = run - bf2f(hb);
      Ap[row*2048 + e]        = hb;
      Ap[row*2048 + 1024 + e] = f2bf_rne(lf);
    }
  } else {
    // ---- k2a: colsum over chunks + init ksum/vsum = S*bias ----
    int idx = (bid-512)*256 + t;   // 0..4095
    int e = idx & 1023;
    int b = (idx >> 10) & 1;
    int j = idx >> 11;
    const float* p = j ? pv : pk;
    float s = 0.f;
    #pragma unroll 8
    for (int c = 0; c < CHUNKS; ++c) s += p[(b*CHUNKS + c)*E_ + e];
    colsum[idx] = s;
    (j ? vsum : ksum)[b*E_ + e] = (float)S_ * (j ? bv : bk)[e];
  }
}

// ===== P3: k2b GEMV, atomicAdd into ksum/vsum (replaces k2b+k2c) =====
__global__ __launch_bounds__(256) void kP3(
    const float* __restrict__ colsum, const float* __restrict__ Wk,
    const float* __restrict__ Wv, float* __restrict__ ksum,
    float* __restrict__ vsum) {
  int f = blockIdx.x;            // 128 blocks
  int j     = f >> 6;
  int slice = (f >> 2) & 15;
  int n     = (f & 3)*256 + threadIdx.x;
  const float* W  = j ? Wv : Wk;
  const float* cs = colsum + j*2048;
  float a0 = 0.f, a1 = 0.f;
  int e0 = slice*64;
  #pragma unroll 8
  for (int i = 0; i < 64; ++i) {
    int e = e0 + i;
    float w = W[(size_t)e*E_ + n];
    a0 += cs[e] * w;
    a1 += cs[1024 + e] * w;
  }
  float* out = j ? vsum : ksum;
  atomicAdd(&out[n], a0);
  atomicAdd(&out[E_ + n], a1);
}

// ========== P4: kG split-bf16 MFMA GEMM (512 blocks) | k3 (128) ==========
#define GNT 48
__global__ __launch_bounds__(256, 2) void kP4(
    const unsigned short* __restrict__ Aq, const unsigned short* __restrict__ Btq,
    const float* __restrict__ bq,
    const unsigned short* __restrict__ Ap, const unsigned short* __restrict__ Btp,
    float* __restrict__ Cq, float* __restrict__ Cp,
    const float* __restrict__ vsum, const float* __restrict__ Wo,
    float* __restrict__ WV) {
  __shared__ __align__(128) char lds[49152];
  int bid = blockIdx.x;
  const int t = threadIdx.x;
  if (bid >= 512) {
    // ---- k3: WV[b,h,n] = vsum[b,h*64+d] dot Wo ----
    int idx = (bid-512)*256 + t;
    int n = idx % E_;
    int h = (idx / E_) % H_;
    int b = idx / (E_*H_);
    float acc = 0.f;
    #pragma unroll 8
    for (int d = 0; d < HD_; ++d)
      acc += vsum[b*E_ + h*HD_ + d] * Wo[(size_t)(h*HD_ + d)*E_ + n];
    WV[idx] = acc;
    return;
  }
  // ---- kG with XCD-aware bijective swizzle over 512 blocks ----
  int wg = bid;
  int newid = (wg & 7)*64 + (wg >> 3);
  int z  = newid >> 8;
  int bm = (newid >> 4) & 15;
  int bn = newid & 15;
  const int lane = t & 63;
  const int wm = (t >> 6) >> 1;
  const int wn = (t >> 6) & 1;

  const unsigned short* A; const unsigned short* Bt;
  const float* bias; float* C;
  if (z == 0) { A = Aq; Bt = Btq; bias = bq;      C = Cq; }
  else        { A = Ap; Bt = Btp; bias = nullptr; C = Cp; }

  // Pre-swizzled global source addresses (rule 21).
  const unsigned short* asrc[4];
  const unsigned short* bsrc[2];
  #pragma unroll
  for (int i = 0; i < 4; ++i) {
    int L = i*4096 + t*16;
    int row = L >> 7, bir = L & 127;
    int sw = bir ^ ((row & 7) << 4);
    asrc[i] = A + (size_t)(bm*128 + row)*2048 + (sw >> 1);
  }
  #pragma unroll
  for (int i = 0; i < 2; ++i) {
    int L = i*4096 + t*16;
    int row = L >> 7, bir = L & 127;
    int sw = bir ^ ((row & 7) << 4);
    bsrc[i] = Bt + (size_t)(bn*64 + row)*2048 + (sw >> 1);
  }
  int aoff[2][4], boff[2][2];
  #pragma unroll
  for (int ks = 0; ks < 2; ++ks) {
    int k0b = (ks*32 + (lane >> 4)*8) * 2;
    #pragma unroll
    for (int mi = 0; mi < 4; ++mi) {
      int row = wm*64 + mi*16 + (lane & 15);
      aoff[ks][mi] = row*128 + (k0b ^ ((row & 7) << 4));
    }
    #pragma unroll
    for (int ni = 0; ni < 2; ++ni) {
      int rown = wn*32 + ni*16 + (lane & 15);
      boff[ks][ni] = rown*128 + (k0b ^ ((rown & 7) << 4));
    }
  }

  f32x4 acc[4][2] = {};

  auto stage = [&](int buf, int kt) {
    int ak = (kt < 32) ? kt : kt - 32;   // A k-block: [hi | lo | hi]
    int bk = (kt < 16) ? kt : kt - 16;   // B k-block: [hi | hi | lo]
    char* Ab = lds + buf*16384;
    char* Bb = lds + 32768 + buf*8192;
    #pragma unroll
    for (int i = 0; i < 4; ++i)
      gload_lds16(asrc[i] + ak*64, Ab + i*4096 + t*16);
    #pragma unroll
    for (int i = 0; i < 2; ++i)
      gload_lds16(bsrc[i] + bk*64, Bb + i*4096 + t*16);
  };

  stage(0, 0);
  __syncthreads();
  int cur = 0;
  for (int kt = 0; kt < GNT; ++kt) {
    if (kt + 1 < GNT) stage(cur ^ 1, kt + 1);
    const char* Ab = lds + cur*16384;
    const char* Bb = lds + 32768 + cur*8192;
    bf16x8 af[2][4], bf_[2][2];
    #pragma unroll
    for (int ks = 0; ks < 2; ++ks) {
      #pragma unroll
      for (int mi = 0; mi < 4; ++mi)
        af[ks][mi] = *(const bf16x8*)(Ab + aoff[ks][mi]);
      #pragma unroll
      for (int ni = 0; ni < 2; ++ni)
        bf_[ks][ni] = *(const bf16x8*)(Bb + boff[ks][ni]);
    }
    #pragma unroll
    for (int ks = 0; ks < 2; ++ks)
      #pragma unroll
      for (int mi = 0; mi < 4; ++mi)
        #pragma unroll
        for (int ni = 0; ni < 2; ++ni)
          acc[mi][ni] = __builtin_amdgcn_mfma_f32_16x16x32_bf16(
              af[ks][mi], bf_[ks][ni], acc[mi][ni], 0, 0, 0);
    __syncthreads();
    cur ^= 1;
  }

  #pragma unroll
  for (int mi = 0; mi < 4; ++mi) {
    #pragma unroll
    for (int ni = 0; ni < 2; ++ni) {
      int col  = bn*64 + wn*32 + ni*16 + (lane & 15);
      int row0 = bm*128 + wm*64 + mi*16 + (lane >> 4)*4;
      float badd = bias ? bias[col] : 0.f;
      #pragma unroll
      for (int j = 0; j < 4; ++j)
        C[(size_t)(row0 + j)*E_ + col] = acc[mi][ni][j] + badd;
    }
  }
}

// ---------------- k6: score row-sums via prefix algebra ----------------
__global__ __launch_bounds__(256) void k6_rs(
    const float* __restrict__ qp, const float* __restrict__ Rpre,
    const float* __restrict__ ksum, const float* __restrict__ U,
    const float* __restrict__ V, float* __restrict__ rs) {
  int w    = blockIdx.x*4 + (threadIdx.x >> 6);
  int lane = threadIdx.x & 63;
  int q = w % S_;
  int h = (w / S_) % H_;
  int b = w / (S_*H_);
  int he = h*HD_ + lane;
  float qv0  = qp[((size_t)(b*S_ + q))*E_ + he];
  float u    = U[he], vv = V[he];
  float ks   = ksum[b*E_ + he];
  float rtot = Rpre[((size_t)(b*S_ + (S_-1)))*E_ + he];
  float tail = rtot;
  if (q <= S_-2) tail -= Rpre[((size_t)(b*S_ + (S_-2-q)))*E_ + he];
  float p = (qv0 + u)*ks + (qv0 + vv)*tail;
  if (q <= S_-3) {
    float qv1 = qp[((size_t)(b*S_ + q + 1))*E_ + he];
    float hd  = Rpre[((size_t)(b*S_ + (S_-3-q)))*E_ + he];
    p += (qv1 + vv)*hd;
  }
  #pragma unroll
  for (int off = 32; off >= 1; off >>= 1)
    p += __shfl_xor(p, off);
  if (lane == 0) rs[(b*H_ + h)*S_ + q] = p * SCALE;
}

// ---------------- k7: out = rs x WV + bo ----------------
__global__ __launch_bounds__(256) void k7_out(
    const float* __restrict__ rs, const float* __restrict__ WV,
    const float* __restrict__ bo, float* __restrict__ out) {
  int idx = blockIdx.x*256 + threadIdx.x;
  int n = idx % E_;
  int q = (idx / E_) % S_;
  int b = idx / (E_*S_);
  float acc = bo[n];
  #pragma unroll
  for (int h = 0; h < H_; ++h)
    acc += rs[(b*H_ + h)*S_ + q] * WV[((size_t)(b*H_ + h))*E_ + n];
  out[idx] = acc;
}

extern "C" void kernel_launch(void* const* d_in, const int* in_sizes, int n_in,
                              void* d_out, int out_size, void* d_ws, size_t ws_size,
                              hipStream_t stream) {
  const float* query = (const float*)d_in[0];
  const float* key   = (const float*)d_in[1];
  const float* value = (const float*)d_in[2];
  const float* pos   = (const float*)d_in[3];
  const float* Wq = (const float*)d_in[4];
  const float* bq = (const float*)d_in[5];
  const float* Wk = (const float*)d_in[6];
  const float* bk = (const float*)d_in[7];
  const float* Wv = (const float*)d_in[8];
  const float* bv = (const float*)d_in[9];
  const float* Wp = (const float*)d_in[10];
  const float* U  = (const float*)d_in[11];
  const float* V  = (const float*)d_in[12];
  const float* Wo = (const float*)d_in[13];
  const float* bo = (const float*)d_in[14];
  float* out = (float*)d_out;
  char* wsb = (char*)d_ws;

  // Compact layout, peak ~34 MB (qproj lives in d_out until k7 overwrites it).
  unsigned short* Aqs = (unsigned short*)(wsb);                       // 8 MB
  unsigned short* Aps = (unsigned short*)(wsb + (8ull<<20));          // 8 MB
  unsigned short* Btq = (unsigned short*)(wsb + (16ull<<20));         // 4 MB
  unsigned short* Btp = (unsigned short*)(wsb + (20ull<<20));         // 4 MB
  float* Rpre  = (float*)(wsb + (24ull<<20));                         // 8 MB
  char*  smallb = wsb + (32ull<<20);
  float* seg   = (float*)(smallb);                                    // 512 KB
  float* pk    = (float*)(smallb + (512ull<<10));                     // 512 KB
  float* pv    = (float*)(smallb + (1024ull<<10));                    // 512 KB
  float* ksum  = (float*)(smallb + (1536ull<<10));                    // 8 KB
  float* vsum  = (float*)(smallb + (1544ull<<10));                    // 8 KB
  float* WVb   = (float*)(smallb + (1552ull<<10));                    // 128 KB
  float* rs    = (float*)(smallb + (1680ull<<10));                    // 128 KB
  float* qproj = out;   // consumed by k6 before k7 rewrites d_out
  float* colsum = (float*)(smallb + (1808ull<<10));                   // 16 KB

  hipLaunchKernelGGL(kP1, dim3(5120), dim3(256), 0, stream,
                     query, pos, key, value, Wq, Wp,
                     seg, Aqs, pk, pv, Btq, Btp);
  hipLaunchKernelGGL(kP2, dim3(528), dim3(256), 0, stream,
                     pos, seg, Aps, pk, pv, bk, bv, colsum, ksum, vsum);
  hipLaunchKernelGGL(kP3, dim3(128), dim3(256), 0, stream,
                     colsum, Wk, Wv, ksum, vsum);
  hipLaunchKernelGGL(kP4, dim3(640), dim3(256), 0, stream,
                     Aqs, Btq, bq, Aps, Btp, qproj, Rpre, vsum, Wo, WVb);
  hipLaunchKernelGGL(k6_rs, dim3(B_*H_*S_/4), dim3(256), 0, stream,
                     qproj, Rpre, ksum, U, V, rs);
  hipLaunchKernelGGL(k7_out, dim3(B_*S_*E_/256), dim3(256), 0, stream,
                     rs, WVb, bo, out);
}

// Round 11
// 176.014 us; speedup vs baseline: 2.1087x; 1.0878x over previous
//
#include <hip/hip_runtime.h>
#include <cstddef>
#include <cstdint>

// Problem constants (fixed by setup_inputs).
#define E_ 1024
#define H_ 16
#define HD_ 64
#define B_ 2
#define S_ 1024
#define NSEG 64
#define SEGLEN (S_/NSEG)          // 16
#define CHUNKS 64
#define CHLEN (S_/CHUNKS)         // 16
#define SCALE 0.03125f            // 1/sqrt(E)

typedef __attribute__((ext_vector_type(8))) short bf16x8;
typedef __attribute__((ext_vector_type(4))) float f32x4;

__device__ __forceinline__ unsigned short f2bf_rne(float x) {
  uint32_t u = __float_as_uint(x);
  uint32_t r = u + 0x7FFFu + ((u >> 16) & 1u);
  return (unsigned short)(r >> 16);
}
__device__ __forceinline__ float bf2f(unsigned short h) {
  return __uint_as_float(((uint32_t)h) << 16);
}
__device__ __forceinline__ void gload_lds16(const void* g, void* l) {
  __builtin_amdgcn_global_load_lds(
      (const __attribute__((address_space(1))) void*)g,
      (__attribute__((address_space(3))) void*)l, 16, 0, 0);
}

// ================= P1: independent prep (kA | kC | kD | k1) =================
// blocks [0,512): kA_segsum   [512,2560): kC_split_q (hi only)
// [2560,4608): kD_splitW (hi only)       [4608,5120): k1_colsum
__global__ __launch_bounds__(256) void kP1(
    const float* __restrict__ query, const float* __restrict__ pos,
    const float* __restrict__ key,   const float* __restrict__ value,
    const float* __restrict__ Wq,    const float* __restrict__ Wp,
    float* __restrict__ seg, unsigned short* __restrict__ Aq,
    float* __restrict__ pk, float* __restrict__ pv,
    unsigned short* __restrict__ Btq, unsigned short* __restrict__ Btp) {
  __shared__ float tile[32][33];
  int bid = blockIdx.x;
  int t = threadIdx.x;
  if (bid < 512) {
    // ---- kA: per-segment sums of pos ----
    int idx = bid*256 + t;
    int e = idx % E_;
    int g = (idx / E_) % NSEG;
    int b = idx / (E_*NSEG);
    const float* p = pos + ((size_t)(b*S_ + g*SEGLEN))*E_ + e;
    float s = 0.f;
    #pragma unroll
    for (int i = 0; i < SEGLEN; ++i) s += p[(size_t)i*E_];
    seg[(b*NSEG + g)*E_ + e] = s;
  } else if (bid < 2560) {
    // ---- kC: query -> bf16 hi only, A'q = [2048][1024] ----
    int idx = (bid-512)*256 + t;
    int e4 = idx & 255;
    int r  = idx >> 8;
    float4 v = ((const float4*)query)[idx];
    ushort4 hi;
    hi.x = f2bf_rne(v.x); hi.y = f2bf_rne(v.y);
    hi.z = f2bf_rne(v.z); hi.w = f2bf_rne(v.w);
    *(ushort4*)&Aq[(size_t)r*1024 + e4*4] = hi;
  } else if (bid < 4608) {
    // ---- kD: transpose Wq/Wp -> B'T hi only, [1024][1024] ----
    int f = bid - 2560;
    int nt = f & 31, kt = (f >> 5) & 31, z = f >> 10;
    const float* W = z ? Wp : Wq;
    unsigned short* Bt = z ? Btp : Btq;
    int lr = t >> 3;
    int lc = (t & 7) * 4;
    float4 v = *(const float4*)&W[(size_t)(kt*32 + lr)*E_ + nt*32 + lc];
    tile[lr][lc+0] = v.x; tile[lr][lc+1] = v.y;
    tile[lr][lc+2] = v.z; tile[lr][lc+3] = v.w;
    __syncthreads();
    int n = nt*32 + lr;
    ushort4 hi;
    hi.x = f2bf_rne(tile[lc+0][lr]); hi.y = f2bf_rne(tile[lc+1][lr]);
    hi.z = f2bf_rne(tile[lc+2][lr]); hi.w = f2bf_rne(tile[lc+3][lr]);
    *(ushort4*)&Bt[(size_t)n*1024 + kt*32 + lc] = hi;
  } else {
    // ---- k1: partial column sums of key and value ----
    int idx = (bid-4608)*256 + t;
    int e = idx % E_;
    int c = (idx / E_) % CHUNKS;
    int b = idx / (E_*CHUNKS);
    const float* kp = key   + ((size_t)(b*S_ + c*CHLEN))*E_ + e;
    const float* vp = value + ((size_t)(b*S_ + c*CHLEN))*E_ + e;
    float sk = 0.f, sv = 0.f;
    #pragma unroll
    for (int s = 0; s < CHLEN; ++s) {
      sk += kp[(size_t)s*E_];
      sv += vp[(size_t)s*E_];
    }
    pk[(b*CHUNKS + c)*E_ + e] = sk;
    pv[(b*CHUNKS + c)*E_ + e] = sv;
  }
}

// ============ P2: kB scan+split | k2a colsum + ksum/vsum init ============
// blocks [0,512): kB (A'p stays hi|lo split: [2048][2048])  [512,528): k2a
__global__ __launch_bounds__(256) void kP2(
    const float* __restrict__ pos, const float* __restrict__ seg,
    unsigned short* __restrict__ Ap,
    const float* __restrict__ pk, const float* __restrict__ pv,
    const float* __restrict__ bk, const float* __restrict__ bv,
    float* __restrict__ colsum, float* __restrict__ ksum,
    float* __restrict__ vsum) {
  int bid = blockIdx.x;
  int t = threadIdx.x;
  if (bid < 512) {
    int idx = bid*256 + t;
    int e = idx % E_;
    int g = (idx / E_) % NSEG;
    int b = idx / (E_*NSEG);
    float run = 0.f;
    for (int gp = 0; gp < g; ++gp) run += seg[(b*NSEG + gp)*E_ + e];
    const float* p = pos + ((size_t)(b*S_ + g*SEGLEN))*E_ + e;
    #pragma unroll
    for (int i = 0; i < SEGLEN; ++i) {
      run += p[(size_t)i*E_];
      size_t row = (size_t)(b*S_ + g*SEGLEN + i);
      unsigned short hb = f2bf_rne(run);
      float lf = run - bf2f(hb);
      Ap[row*2048 + e]        = hb;
      Ap[row*2048 + 1024 + e] = f2bf_rne(lf);
    }
  } else {
    int idx = (bid-512)*256 + t;   // 0..4095
    int e = idx & 1023;
    int b = (idx >> 10) & 1;
    int j = idx >> 11;
    const float* p = j ? pv : pk;
    float s = 0.f;
    #pragma unroll 8
    for (int c = 0; c < CHUNKS; ++c) s += p[(b*CHUNKS + c)*E_ + e];
    colsum[idx] = s;
    (j ? vsum : ksum)[b*E_ + e] = (float)S_ * (j ? bv : bk)[e];
  }
}

// ===== P3: k2b GEMV, atomicAdd into ksum/vsum =====
__global__ __launch_bounds__(256) void kP3(
    const float* __restrict__ colsum, const float* __restrict__ Wk,
    const float* __restrict__ Wv, float* __restrict__ ksum,
    float* __restrict__ vsum) {
  int f = blockIdx.x;            // 128 blocks
  int j     = f >> 6;
  int slice = (f >> 2) & 15;
  int n     = (f & 3)*256 + threadIdx.x;
  const float* W  = j ? Wv : Wk;
  const float* cs = colsum + j*2048;
  float a0 = 0.f, a1 = 0.f;
  int e0 = slice*64;
  #pragma unroll 8
  for (int i = 0; i < 64; ++i) {
    int e = e0 + i;
    float w = W[(size_t)e*E_ + n];
    a0 += cs[e] * w;
    a1 += cs[1024 + e] * w;
  }
  float* out = j ? vsum : ksum;
  atomicAdd(&out[n], a0);
  atomicAdd(&out[E_ + n], a1);
}

// ========== P4: kG MFMA GEMM (512 blocks) | k3 (128 blocks) ==========
// z=0: Cq = query @ Wq + bq  (1-product: Ah*Bh, 16 k-tiles)
// z=1: Cp = prefix(pos) @ Wp (2-product: Ah*Bh + Al*Bh, 32 k-tiles)
__global__ __launch_bounds__(256, 2) void kP4(
    const unsigned short* __restrict__ Aq, const unsigned short* __restrict__ Btq,
    const float* __restrict__ bq,
    const unsigned short* __restrict__ Ap, const unsigned short* __restrict__ Btp,
    float* __restrict__ Cq, float* __restrict__ Cp,
    const float* __restrict__ vsum, const float* __restrict__ Wo,
    float* __restrict__ WV) {
  __shared__ __align__(128) char lds[49152];
  int bid = blockIdx.x;
  const int t = threadIdx.x;
  if (bid >= 512) {
    // ---- k3: WV[b,h,n] = vsum[b,h*64+d] dot Wo ----
    int idx = (bid-512)*256 + t;
    int n = idx % E_;
    int h = (idx / E_) % H_;
    int b = idx / (E_*H_);
    float acc = 0.f;
    #pragma unroll 8
    for (int d = 0; d < HD_; ++d)
      acc += vsum[b*E_ + h*HD_ + d] * Wo[(size_t)(h*HD_ + d)*E_ + n];
    WV[idx] = acc;
    return;
  }
  // ---- kG with XCD-aware bijective swizzle over 512 blocks ----
  int wg = bid;
  int newid = (wg & 7)*64 + (wg >> 3);
  int z  = newid >> 8;
  int bm = (newid >> 4) & 15;
  int bn = newid & 15;
  const int lane = t & 63;
  const int wm = (t >> 6) >> 1;
  const int wn = (t >> 6) & 1;

  const unsigned short* A; const unsigned short* Bt;
  const float* bias; float* C;
  int alen, ntot;
  if (z == 0) { A = Aq; Bt = Btq; bias = bq;      C = Cq; alen = 1024; ntot = 16; }
  else        { A = Ap; Bt = Btp; bias = nullptr; C = Cp; alen = 2048; ntot = 32; }

  // Pre-swizzled global source addresses (rule 21).
  const unsigned short* asrc[4];
  const unsigned short* bsrc[2];
  #pragma unroll
  for (int i = 0; i < 4; ++i) {
    int L = i*4096 + t*16;
    int row = L >> 7, bir = L & 127;
    int sw = bir ^ ((row & 7) << 4);
    asrc[i] = A + (size_t)(bm*128 + row)*alen + (sw >> 1);
  }
  #pragma unroll
  for (int i = 0; i < 2; ++i) {
    int L = i*4096 + t*16;
    int row = L >> 7, bir = L & 127;
    int sw = bir ^ ((row & 7) << 4);
    bsrc[i] = Bt + (size_t)(bn*64 + row)*1024 + (sw >> 1);
  }
  int aoff[2][4], boff[2][2];
  #pragma unroll
  for (int ks = 0; ks < 2; ++ks) {
    int k0b = (ks*32 + (lane >> 4)*8) * 2;
    #pragma unroll
    for (int mi = 0; mi < 4; ++mi) {
      int row = wm*64 + mi*16 + (lane & 15);
      aoff[ks][mi] = row*128 + (k0b ^ ((row & 7) << 4));
    }
    #pragma unroll
    for (int ni = 0; ni < 2; ++ni) {
      int rown = wn*32 + ni*16 + (lane & 15);
      boff[ks][ni] = rown*128 + (k0b ^ ((rown & 7) << 4));
    }
  }

  f32x4 acc[4][2] = {};

  auto stage = [&](int buf, int kt) {
    int ak = kt;                           // z=0: [0,16) hi; z=1: [0,32) hi|lo
    int bk = (kt < 16) ? kt : kt - 16;     // B always hi
    char* Ab = lds + buf*16384;
    char* Bb = lds + 32768 + buf*8192;
    #pragma unroll
    for (int i = 0; i < 4; ++i)
      gload_lds16(asrc[i] + ak*64, Ab + i*4096 + t*16);
    #pragma unroll
    for (int i = 0; i < 2; ++i)
      gload_lds16(bsrc[i] + bk*64, Bb + i*4096 + t*16);
  };

  stage(0, 0);
  __syncthreads();
  int cur = 0;
  for (int kt = 0; kt < ntot; ++kt) {
    if (kt + 1 < ntot) stage(cur ^ 1, kt + 1);
    const char* Ab = lds + cur*16384;
    const char* Bb = lds + 32768 + cur*8192;
    bf16x8 af[2][4], bf_[2][2];
    #pragma unroll
    for (int ks = 0; ks < 2; ++ks) {
      #pragma unroll
      for (int mi = 0; mi < 4; ++mi)
        af[ks][mi] = *(const bf16x8*)(Ab + aoff[ks][mi]);
      #pragma unroll
      for (int ni = 0; ni < 2; ++ni)
        bf_[ks][ni] = *(const bf16x8*)(Bb + boff[ks][ni]);
    }
    #pragma unroll
    for (int ks = 0; ks < 2; ++ks)
      #pragma unroll
      for (int mi = 0; mi < 4; ++mi)
        #pragma unroll
        for (int ni = 0; ni < 2; ++ni)
          acc[mi][ni] = __builtin_amdgcn_mfma_f32_16x16x32_bf16(
              af[ks][mi], bf_[ks][ni], acc[mi][ni], 0, 0, 0);
    __syncthreads();
    cur ^= 1;
  }

  #pragma unroll
  for (int mi = 0; mi < 4; ++mi) {
    #pragma unroll
    for (int ni = 0; ni < 2; ++ni) {
      int col  = bn*64 + wn*32 + ni*16 + (lane & 15);
      int row0 = bm*128 + wm*64 + mi*16 + (lane >> 4)*4;
      float badd = bias ? bias[col] : 0.f;
      #pragma unroll
      for (int j = 0; j < 4; ++j)
        C[(size_t)(row0 + j)*E_ + col] = acc[mi][ni][j] + badd;
    }
  }
}

// ===== kFin: fused k6 (row-sums) + k7 (out GEMV). One block per (b,q). =====
__global__ __launch_bounds__(256) void kFin(
    const float* __restrict__ qp, const float* __restrict__ Rpre,
    const float* __restrict__ ksum, const float* __restrict__ U,
    const float* __restrict__ V, const float* __restrict__ WV,
    const float* __restrict__ bo, float* __restrict__ out) {
  __shared__ float rsL[H_];
  int bq = blockIdx.x;
  int b = bq >> 10, q = bq & 1023;
  int t = threadIdx.x;
  int w = t >> 6, lane = t & 63;
  const float* qrow0 = qp + ((size_t)(b*S_ + q))*E_;
  const float* rt    = Rpre + ((size_t)(b*S_ + (S_-1)))*E_;
  #pragma unroll
  for (int i = 0; i < 4; ++i) {
    int h = w*4 + i;
    int he = h*HD_ + lane;
    float qv0 = qrow0[he];
    float u = U[he], vv = V[he];
    float ks = ksum[b*E_ + he];
    float tail = rt[he];
    if (q <= S_-2) tail -= Rpre[((size_t)(b*S_ + (S_-2-q)))*E_ + he];
    float p = (qv0 + u)*ks + (qv0 + vv)*tail;
    if (q <= S_-3) {
      float qv1 = qrow0[E_ + he];   // row q+1
      p += (qv1 + vv)*Rpre[((size_t)(b*S_ + (S_-3-q)))*E_ + he];
    }
    #pragma unroll
    for (int off = 32; off >= 1; off >>= 1)
      p += __shfl_xor(p, off);
    if (lane == 0) rsL[h] = p * SCALE;
  }
  __syncthreads();
  #pragma unroll
  for (int i = 0; i < 4; ++i) {
    int n = i*256 + t;
    float acc = bo[n];
    #pragma unroll
    for (int h = 0; h < H_; ++h)
      acc += rsL[h] * WV[((size_t)(b*H_ + h))*E_ + n];
    out[((size_t)(b*S_ + q))*E_ + n] = acc;
  }
}

extern "C" void kernel_launch(void* const* d_in, const int* in_sizes, int n_in,
                              void* d_out, int out_size, void* d_ws, size_t ws_size,
                              hipStream_t stream) {
  const float* query = (const float*)d_in[0];
  const float* key   = (const float*)d_in[1];
  const float* value = (const float*)d_in[2];
  const float* pos   = (const float*)d_in[3];
  const float* Wq = (const float*)d_in[4];
  const float* bq = (const float*)d_in[5];
  const float* Wk = (const float*)d_in[6];
  const float* bk = (const float*)d_in[7];
  const float* Wv = (const float*)d_in[8];
  const float* bv = (const float*)d_in[9];
  const float* Wp = (const float*)d_in[10];
  const float* U  = (const float*)d_in[11];
  const float* V  = (const float*)d_in[12];
  const float* Wo = (const float*)d_in[13];
  const float* bo = (const float*)d_in[14];
  float* out = (float*)d_out;
  char* wsb = (char*)d_ws;

  // Peak ~34 MB (same proven footprint); qproj now in ws (kFin needs d_out free).
  unsigned short* Aqs = (unsigned short*)(wsb);                       // 4 MB [2048][1024]
  unsigned short* Aps = (unsigned short*)(wsb + (4ull<<20));          // 8 MB [2048][2048]
  unsigned short* Btq = (unsigned short*)(wsb + (12ull<<20));         // 2 MB [1024][1024]
  unsigned short* Btp = (unsigned short*)(wsb + (14ull<<20));         // 2 MB [1024][1024]
  float* Rpre  = (float*)(wsb + (16ull<<20));                         // 8 MB
  float* qproj = (float*)(wsb + (24ull<<20));                         // 8 MB
  char*  smallb = wsb + (32ull<<20);
  float* seg   = (float*)(smallb);                                    // 512 KB
  float* pk    = (float*)(smallb + (512ull<<10));                     // 512 KB
  float* pv    = (float*)(smallb + (1024ull<<10));                    // 512 KB
  float* ksum  = (float*)(smallb + (1536ull<<10));                    // 8 KB
  float* vsum  = (float*)(smallb + (1544ull<<10));                    // 8 KB
  float* WVb   = (float*)(smallb + (1552ull<<10));                    // 128 KB
  float* colsum = (float*)(smallb + (1680ull<<10));                   // 16 KB

  hipLaunchKernelGGL(kP1, dim3(5120), dim3(256), 0, stream,
                     query, pos, key, value, Wq, Wp,
                     seg, Aqs, pk, pv, Btq, Btp);
  hipLaunchKernelGGL(kP2, dim3(528), dim3(256), 0, stream,
                     pos, seg, Aps, pk, pv, bk, bv, colsum, ksum, vsum);
  hipLaunchKernelGGL(kP3, dim3(128), dim3(256), 0, stream,
                     colsum, Wk, Wv, ksum, vsum);
  hipLaunchKernelGGL(kP4, dim3(640), dim3(256), 0, stream,
                     Aqs, Btq, bq, Aps, Btp, qproj, Rpre, vsum, Wo, WVb);
  hipLaunchKernelGGL(kFin, dim3(B_*S_), dim3(256), 0, stream,
                     qproj, Rpre, ksum, U, V, WVb, bo, out);
}

// Round 12
// 169.757 us; speedup vs baseline: 2.1864x; 1.0369x over previous
//
#include <hip/hip_runtime.h>
#include <cstddef>
#include <cstdint>

// Problem constants (fixed by setup_inputs).
#define E_ 1024
#define H_ 16
#define HD_ 64
#define B_ 2
#define S_ 1024
#define NSEG 64
#define SEGLEN (S_/NSEG)          // 16
#define CHUNKS 64
#define CHLEN (S_/CHUNKS)         // 16
#define SCALE 0.03125f            // 1/sqrt(E)

typedef __attribute__((ext_vector_type(8))) short bf16x8;
typedef __attribute__((ext_vector_type(4))) float f32x4;

__device__ __forceinline__ unsigned short f2bf_rne(float x) {
  uint32_t u = __float_as_uint(x);
  uint32_t r = u + 0x7FFFu + ((u >> 16) & 1u);
  return (unsigned short)(r >> 16);
}
__device__ __forceinline__ float bf2f(unsigned short h) {
  return __uint_as_float(((uint32_t)h) << 16);
}
__device__ __forceinline__ void gload_lds16(const void* g, void* l) {
  __builtin_amdgcn_global_load_lds(
      (const __attribute__((address_space(1))) void*)g,
      (__attribute__((address_space(3))) void*)l, 16, 0, 0);
}

// ========== P1: independent prep (kA | kC | kD | k1 | bias-init) ==========
// [0,512): kA_segsum          [512,2560): kC_split_q (hi only)
// [2560,4608): kD_splitW (hi) [4608,5120): k1_colsum  [5120,5136): init
__global__ __launch_bounds__(256) void kP1(
    const float* __restrict__ query, const float* __restrict__ pos,
    const float* __restrict__ key,   const float* __restrict__ value,
    const float* __restrict__ Wq,    const float* __restrict__ Wp,
    const float* __restrict__ bk,    const float* __restrict__ bv,
    float* __restrict__ seg, unsigned short* __restrict__ Aq,
    float* __restrict__ pk, float* __restrict__ pv,
    unsigned short* __restrict__ Btq, unsigned short* __restrict__ Btp,
    float* __restrict__ ksum, float* __restrict__ vsum) {
  __shared__ float tile[32][33];
  int bid = blockIdx.x;
  int t = threadIdx.x;
  if (bid < 512) {
    // ---- kA: per-segment sums of pos ----
    int idx = bid*256 + t;
    int e = idx % E_;
    int g = (idx / E_) % NSEG;
    int b = idx / (E_*NSEG);
    const float* p = pos + ((size_t)(b*S_ + g*SEGLEN))*E_ + e;
    float s = 0.f;
    #pragma unroll
    for (int i = 0; i < SEGLEN; ++i) s += p[(size_t)i*E_];
    seg[(b*NSEG + g)*E_ + e] = s;
  } else if (bid < 2560) {
    // ---- kC: query -> bf16 hi only, A'q = [2048][1024] ----
    int idx = (bid-512)*256 + t;
    int e4 = idx & 255;
    int r  = idx >> 8;
    float4 v = ((const float4*)query)[idx];
    ushort4 hi;
    hi.x = f2bf_rne(v.x); hi.y = f2bf_rne(v.y);
    hi.z = f2bf_rne(v.z); hi.w = f2bf_rne(v.w);
    *(ushort4*)&Aq[(size_t)r*1024 + e4*4] = hi;
  } else if (bid < 4608) {
    // ---- kD: transpose Wq/Wp -> B'T hi only, [1024][1024] ----
    int f = bid - 2560;
    int nt = f & 31, kt = (f >> 5) & 31, z = f >> 10;
    const float* W = z ? Wp : Wq;
    unsigned short* Bt = z ? Btp : Btq;
    int lr = t >> 3;
    int lc = (t & 7) * 4;
    float4 v = *(const float4*)&W[(size_t)(kt*32 + lr)*E_ + nt*32 + lc];
    tile[lr][lc+0] = v.x; tile[lr][lc+1] = v.y;
    tile[lr][lc+2] = v.z; tile[lr][lc+3] = v.w;
    __syncthreads();
    int n = nt*32 + lr;
    ushort4 hi;
    hi.x = f2bf_rne(tile[lc+0][lr]); hi.y = f2bf_rne(tile[lc+1][lr]);
    hi.z = f2bf_rne(tile[lc+2][lr]); hi.w = f2bf_rne(tile[lc+3][lr]);
    *(ushort4*)&Bt[(size_t)n*1024 + kt*32 + lc] = hi;
  } else if (bid < 5120) {
    // ---- k1: partial column sums of key and value ----
    int idx = (bid-4608)*256 + t;
    int e = idx % E_;
    int c = (idx / E_) % CHUNKS;
    int b = idx / (E_*CHUNKS);
    const float* kp = key   + ((size_t)(b*S_ + c*CHLEN))*E_ + e;
    const float* vp = value + ((size_t)(b*S_ + c*CHLEN))*E_ + e;
    float sk = 0.f, sv = 0.f;
    #pragma unroll
    for (int s = 0; s < CHLEN; ++s) {
      sk += kp[(size_t)s*E_];
      sv += vp[(size_t)s*E_];
    }
    pk[(b*CHUNKS + c)*E_ + e] = sk;
    pv[(b*CHUNKS + c)*E_ + e] = sv;
  } else {
    // ---- init: ksum/vsum = S*bias (atomics accumulate on top in kP2) ----
    int idx = (bid-5120)*256 + t;   // 0..4095
    int e = idx & 1023;
    int b = (idx >> 10) & 1;
    int j = idx >> 11;
    (j ? vsum : ksum)[b*E_ + e] = (float)S_ * (j ? bv : bk)[e];
  }
}

// ======== P2: kB scan+split | fused colsum+GEMV (atomic ksum/vsum) ========
// [0,512): kB   [512,544): one block per (j, 64-row e-slice)
__global__ __launch_bounds__(256) void kP2(
    const float* __restrict__ pos, const float* __restrict__ seg,
    unsigned short* __restrict__ Ap,
    const float* __restrict__ pk, const float* __restrict__ pv,
    const float* __restrict__ Wk, const float* __restrict__ Wv,
    float* __restrict__ ksum, float* __restrict__ vsum) {
  int bid = blockIdx.x;
  int t = threadIdx.x;
  if (bid < 512) {
    // ---- kB: inclusive prefix-scan of pos, fused split-bf16 write ----
    int idx = bid*256 + t;
    int e = idx % E_;
    int g = (idx / E_) % NSEG;
    int b = idx / (E_*NSEG);
    float run = 0.f;
    for (int gp = 0; gp < g; ++gp) run += seg[(b*NSEG + gp)*E_ + e];
    const float* p = pos + ((size_t)(b*S_ + g*SEGLEN))*E_ + e;
    #pragma unroll
    for (int i = 0; i < SEGLEN; ++i) {
      run += p[(size_t)i*E_];
      size_t row = (size_t)(b*S_ + g*SEGLEN + i);
      unsigned short hb = f2bf_rne(run);
      float lf = run - bf2f(hb);
      Ap[row*2048 + e]        = hb;
      Ap[row*2048 + 1024 + e] = f2bf_rne(lf);
    }
  } else {
    // ---- fused: recompute 64-e-slice colsums from pk/pv, then GEMV ----
    __shared__ float csL[2][64];
    int f = bid - 512;             // 0..31
    int j     = f >> 4;            // 0: key, 1: value
    int slice = f & 15;
    int e0 = slice*64;
    const float* p = j ? pv : pk;
    int pair = t >> 1;             // 0..127 -> (b, el)
    int half = t & 1;
    int b  = pair >> 6;
    int el = pair & 63;
    float s = 0.f;
    #pragma unroll 8
    for (int c = half*32; c < half*32 + 32; ++c)
      s += p[(size_t)(b*CHUNKS + c)*E_ + e0 + el];
    s += __shfl_xor(s, 1);
    if (half == 0) csL[b][el] = s;
    __syncthreads();
    const float* W = j ? Wv : Wk;
    float* outp = j ? vsum : ksum;
    #pragma unroll
    for (int i = 0; i < 4; ++i) {
      int n = i*256 + t;
      float a0 = 0.f, a1 = 0.f;
      #pragma unroll 8
      for (int e = 0; e < 64; ++e) {
        float w = W[(size_t)(e0 + e)*E_ + n];
        a0 += csL[0][e] * w;
        a1 += csL[1][e] * w;
      }
      atomicAdd(&outp[n], a0);
      atomicAdd(&outp[E_ + n], a1);
    }
  }
}

// ========== P4: kG MFMA GEMM (512 blocks) | k3 (128 blocks) ==========
// z=0: Cq = query @ Wq + bq  (1-product: Ah*Bh, 16 k-tiles)
// z=1: Cp = prefix(pos) @ Wp (2-product: Ah*Bh + Al*Bh, 32 k-tiles)
__global__ __launch_bounds__(256, 2) void kP4(
    const unsigned short* __restrict__ Aq, const unsigned short* __restrict__ Btq,
    const float* __restrict__ bq,
    const unsigned short* __restrict__ Ap, const unsigned short* __restrict__ Btp,
    float* __restrict__ Cq, float* __restrict__ Cp,
    const float* __restrict__ vsum, const float* __restrict__ Wo,
    float* __restrict__ WV) {
  __shared__ __align__(128) char lds[49152];
  int bid = blockIdx.x;
  const int t = threadIdx.x;
  if (bid >= 512) {
    // ---- k3: WV[b,h,n] = vsum[b,h*64+d] dot Wo ----
    int idx = (bid-512)*256 + t;
    int n = idx % E_;
    int h = (idx / E_) % H_;
    int b = idx / (E_*H_);
    float acc = 0.f;
    #pragma unroll 8
    for (int d = 0; d < HD_; ++d)
      acc += vsum[b*E_ + h*HD_ + d] * Wo[(size_t)(h*HD_ + d)*E_ + n];
    WV[idx] = acc;
    return;
  }
  // ---- kG with XCD-aware bijective swizzle over 512 blocks ----
  int wg = bid;
  int newid = (wg & 7)*64 + (wg >> 3);
  int z  = newid >> 8;
  int bm = (newid >> 4) & 15;
  int bn = newid & 15;
  const int lane = t & 63;
  const int wm = (t >> 6) >> 1;
  const int wn = (t >> 6) & 1;

  const unsigned short* A; const unsigned short* Bt;
  const float* bias; float* C;
  int alen, ntot;
  if (z == 0) { A = Aq; Bt = Btq; bias = bq;      C = Cq; alen = 1024; ntot = 16; }
  else        { A = Ap; Bt = Btp; bias = nullptr; C = Cp; alen = 2048; ntot = 32; }

  // Pre-swizzled global source addresses (rule 21).
  const unsigned short* asrc[4];
  const unsigned short* bsrc[2];
  #pragma unroll
  for (int i = 0; i < 4; ++i) {
    int L = i*4096 + t*16;
    int row = L >> 7, bir = L & 127;
    int sw = bir ^ ((row & 7) << 4);
    asrc[i] = A + (size_t)(bm*128 + row)*alen + (sw >> 1);
  }
  #pragma unroll
  for (int i = 0; i < 2; ++i) {
    int L = i*4096 + t*16;
    int row = L >> 7, bir = L & 127;
    int sw = bir ^ ((row & 7) << 4);
    bsrc[i] = Bt + (size_t)(bn*64 + row)*1024 + (sw >> 1);
  }
  int aoff[2][4], boff[2][2];
  #pragma unroll
  for (int ks = 0; ks < 2; ++ks) {
    int k0b = (ks*32 + (lane >> 4)*8) * 2;
    #pragma unroll
    for (int mi = 0; mi < 4; ++mi) {
      int row = wm*64 + mi*16 + (lane & 15);
      aoff[ks][mi] = row*128 + (k0b ^ ((row & 7) << 4));
    }
    #pragma unroll
    for (int ni = 0; ni < 2; ++ni) {
      int rown = wn*32 + ni*16 + (lane & 15);
      boff[ks][ni] = rown*128 + (k0b ^ ((rown & 7) << 4));
    }
  }

  f32x4 acc[4][2] = {};

  auto stage = [&](int buf, int kt) {
    int ak = kt;                           // z=0: [0,16) hi; z=1: [0,32) hi|lo
    int bk = (kt < 16) ? kt : kt - 16;     // B always hi
    char* Ab = lds + buf*16384;
    char* Bb = lds + 32768 + buf*8192;
    #pragma unroll
    for (int i = 0; i < 4; ++i)
      gload_lds16(asrc[i] + ak*64, Ab + i*4096 + t*16);
    #pragma unroll
    for (int i = 0; i < 2; ++i)
      gload_lds16(bsrc[i] + bk*64, Bb + i*4096 + t*16);
  };

  stage(0, 0);
  __syncthreads();
  int cur = 0;
  for (int kt = 0; kt < ntot; ++kt) {
    if (kt + 1 < ntot) stage(cur ^ 1, kt + 1);
    const char* Ab = lds + cur*16384;
    const char* Bb = lds + 32768 + cur*8192;
    bf16x8 af[2][4], bf_[2][2];
    #pragma unroll
    for (int ks = 0; ks < 2; ++ks) {
      #pragma unroll
      for (int mi = 0; mi < 4; ++mi)
        af[ks][mi] = *(const bf16x8*)(Ab + aoff[ks][mi]);
      #pragma unroll
      for (int ni = 0; ni < 2; ++ni)
        bf_[ks][ni] = *(const bf16x8*)(Bb + boff[ks][ni]);
    }
    #pragma unroll
    for (int ks = 0; ks < 2; ++ks)
      #pragma unroll
      for (int mi = 0; mi < 4; ++mi)
        #pragma unroll
        for (int ni = 0; ni < 2; ++ni)
          acc[mi][ni] = __builtin_amdgcn_mfma_f32_16x16x32_bf16(
              af[ks][mi], bf_[ks][ni], acc[mi][ni], 0, 0, 0);
    __syncthreads();
    cur ^= 1;
  }

  #pragma unroll
  for (int mi = 0; mi < 4; ++mi) {
    #pragma unroll
    for (int ni = 0; ni < 2; ++ni) {
      int col  = bn*64 + wn*32 + ni*16 + (lane & 15);
      int row0 = bm*128 + wm*64 + mi*16 + (lane >> 4)*4;
      float badd = bias ? bias[col] : 0.f;
      #pragma unroll
      for (int j = 0; j < 4; ++j)
        C[(size_t)(row0 + j)*E_ + col] = acc[mi][ni][j] + badd;
    }
  }
}

// ===== kFin: fused k6 (row-sums) + k7 (out GEMV). One block per (b,q). =====
__global__ __launch_bounds__(256) void kFin(
    const float* __restrict__ qp, const float* __restrict__ Rpre,
    const float* __restrict__ ksum, const float* __restrict__ U,
    const float* __restrict__ V, const float* __restrict__ WV,
    const float* __restrict__ bo, float* __restrict__ out) {
  __shared__ float rsL[H_];
  int bq = blockIdx.x;
  int b = bq >> 10, q = bq & 1023;
  int t = threadIdx.x;
  int w = t >> 6, lane = t & 63;
  const float* qrow0 = qp + ((size_t)(b*S_ + q))*E_;
  const float* rt    = Rpre + ((size_t)(b*S_ + (S_-1)))*E_;
  #pragma unroll
  for (int i = 0; i < 4; ++i) {
    int h = w*4 + i;
    int he = h*HD_ + lane;
    float qv0 = qrow0[he];
    float u = U[he], vv = V[he];
    float ks = ksum[b*E_ + he];
    float tail = rt[he];
    if (q <= S_-2) tail -= Rpre[((size_t)(b*S_ + (S_-2-q)))*E_ + he];
    float p = (qv0 + u)*ks + (qv0 + vv)*tail;
    if (q <= S_-3) {
      float qv1 = qrow0[E_ + he];   // row q+1
      p += (qv1 + vv)*Rpre[((size_t)(b*S_ + (S_-3-q)))*E_ + he];
    }
    #pragma unroll
    for (int off = 32; off >= 1; off >>= 1)
      p += __shfl_xor(p, off);
    if (lane == 0) rsL[h] = p * SCALE;
  }
  __syncthreads();
  #pragma unroll
  for (int i = 0; i < 4; ++i) {
    int n = i*256 + t;
    float acc = bo[n];
    #pragma unroll
    for (int h = 0; h < H_; ++h)
      acc += rsL[h] * WV[((size_t)(b*H_ + h))*E_ + n];
    out[((size_t)(b*S_ + q))*E_ + n] = acc;
  }
}

extern "C" void kernel_launch(void* const* d_in, const int* in_sizes, int n_in,
                              void* d_out, int out_size, void* d_ws, size_t ws_size,
                              hipStream_t stream) {
  const float* query = (const float*)d_in[0];
  const float* key   = (const float*)d_in[1];
  const float* value = (const float*)d_in[2];
  const float* pos   = (const float*)d_in[3];
  const float* Wq = (const float*)d_in[4];
  const float* bq = (const float*)d_in[5];
  const float* Wk = (const float*)d_in[6];
  const float* bk = (const float*)d_in[7];
  const float* Wv = (const float*)d_in[8];
  const float* bv = (const float*)d_in[9];
  const float* Wp = (const float*)d_in[10];
  const float* U  = (const float*)d_in[11];
  const float* V  = (const float*)d_in[12];
  const float* Wo = (const float*)d_in[13];
  const float* bo = (const float*)d_in[14];
  float* out = (float*)d_out;
  char* wsb = (char*)d_ws;

  // Peak ~34 MB; qproj in ws (kFin needs d_out free of cross-block hazards).
  unsigned short* Aqs = (unsigned short*)(wsb);                       // 4 MB [2048][1024]
  unsigned short* Aps = (unsigned short*)(wsb + (4ull<<20));          // 8 MB [2048][2048]
  unsigned short* Btq = (unsigned short*)(wsb + (12ull<<20));         // 2 MB [1024][1024]
  unsigned short* Btp = (unsigned short*)(wsb + (14ull<<20));         // 2 MB [1024][1024]
  float* Rpre  = (float*)(wsb + (16ull<<20));                         // 8 MB
  float* qproj = (float*)(wsb + (24ull<<20));                         // 8 MB
  char*  smallb = wsb + (32ull<<20);
  float* seg   = (float*)(smallb);                                    // 512 KB
  float* pk    = (float*)(smallb + (512ull<<10));                     // 512 KB
  float* pv    = (float*)(smallb + (1024ull<<10));                    // 512 KB
  float* ksum  = (float*)(smallb + (1536ull<<10));                    // 8 KB
  float* vsum  = (float*)(smallb + (1544ull<<10));                    // 8 KB
  float* WVb   = (float*)(smallb + (1552ull<<10));                    // 128 KB

  hipLaunchKernelGGL(kP1, dim3(5136), dim3(256), 0, stream,
                     query, pos, key, value, Wq, Wp, bk, bv,
                     seg, Aqs, pk, pv, Btq, Btp, ksum, vsum);
  hipLaunchKernelGGL(kP2, dim3(544), dim3(256), 0, stream,
                     pos, seg, Aps, pk, pv, Wk, Wv, ksum, vsum);
  hipLaunchKernelGGL(kP4, dim3(640), dim3(256), 0, stream,
                     Aqs, Btq, bq, Aps, Btp, qproj, Rpre, vsum, Wo, WVb);
  hipLaunchKernelGGL(kFin, dim3(B_*S_), dim3(256), 0, stream,
                     qproj, Rpre, ksum, U, V, WVb, bo, out);
}